// Round 2
// baseline (273.492 us; speedup 1.0000x reference)
//
#include <hip/hip_runtime.h>
#include <hip/hip_bf16.h>

// Problem: B=8, N=4096, M=2048, IN=512, D=512, CTX=768
// out = h + attn @ f2,  attn = softmax(h W_a^T),  f2^T = W_out W_v G W_k^T,
// G = X^T X (symmetric), X = [h; h_retrieved W_c^T]  (all bf16 MFMA internally)

typedef unsigned short u16;
typedef __bf16 bf16x8 __attribute__((ext_vector_type(8)));
typedef float  f32x4  __attribute__((ext_vector_type(4)));
typedef float  f32v4  __attribute__((ext_vector_type(4)));
typedef u16    u16v4  __attribute__((ext_vector_type(4)));
typedef u16    u16v8  __attribute__((ext_vector_type(8)));

__device__ __forceinline__ u16 f2bf(float f) {
  unsigned u = __builtin_bit_cast(unsigned, f);
  u = u + 0x7FFFu + ((u >> 16) & 1u);   // RNE; inputs are finite
  return (u16)(u >> 16);
}
__device__ __forceinline__ float bf2f(u16 s) {
  return __builtin_bit_cast(float, (unsigned)s << 16);
}

// ---------------- elementwise f32 -> bf16 ----------------
__global__ __launch_bounds__(256) void cvt_f32_bf16(const float* __restrict__ in,
                                                    u16* __restrict__ out, long n) {
  long i = (((long)blockIdx.x * 256) + threadIdx.x) * 8;
  if (i >= n) return;
  f32v4 a = *(const f32v4*)(in + i);
  f32v4 b = *(const f32v4*)(in + i + 4);
  u16v8 o;
  o[0] = f2bf(a[0]); o[1] = f2bf(a[1]); o[2] = f2bf(a[2]); o[3] = f2bf(a[3]);
  o[4] = f2bf(b[0]); o[5] = f2bf(b[1]); o[6] = f2bf(b[2]); o[7] = f2bf(b[3]);
  *(u16v8*)(out + i) = o;
}

// ---------------- tiled bf16 transpose: dst[c,r] = src[r,c] ----------------
__global__ __launch_bounds__(256) void transpose_bf16(const u16* __restrict__ src,
                                                      u16* __restrict__ dst,
                                                      int src_ld, int dst_ld,
                                                      long src_bs, long dst_bs) {
  __shared__ u16 tile[64][72];   // +8 pad breaks bank conflicts
  long b = blockIdx.z;
  const u16* S = src + b * src_bs;
  u16* D = dst + b * dst_bs;
  int r0 = blockIdx.x * 64;
  int c0 = blockIdx.y * 64;
  int t  = threadIdx.x;
  int tr = t >> 3;          // 0..31
  int tc = (t & 7) * 8;     // 0..56
#pragma unroll
  for (int it = 0; it < 2; ++it) {
    int rr = it * 32 + tr;
    *(u16v8*)&tile[rr][tc] = *(const u16v8*)&S[(long)(r0 + rr) * src_ld + c0 + tc];
  }
  __syncthreads();
#pragma unroll
  for (int it = 0; it < 2; ++it) {
    int cr = it * 32 + tr;
    u16v8 o;
#pragma unroll
    for (int j = 0; j < 8; ++j) o[j] = tile[tc + j][cr];
    *(u16v8*)&D[(long)(c0 + cr) * dst_ld + r0 + tc] = o;
  }
}

// ---------------- row softmax over 512 bf16 (in place), 1 wave/row ----------------
__global__ __launch_bounds__(256) void softmax512(u16* __restrict__ data) {
  long row = (long)blockIdx.x * 4 + (threadIdx.x >> 6);
  int lane = threadIdx.x & 63;
  u16* p = data + row * 512 + lane * 8;
  u16v8 raw = *(const u16v8*)p;
  float v[8];
  float mx = -3.0e38f;
#pragma unroll
  for (int j = 0; j < 8; ++j) { v[j] = bf2f(raw[j]); mx = fmaxf(mx, v[j]); }
#pragma unroll
  for (int o = 32; o > 0; o >>= 1) mx = fmaxf(mx, __shfl_xor(mx, o, 64));
  float sm = 0.f;
#pragma unroll
  for (int j = 0; j < 8; ++j) { v[j] = __expf(v[j] - mx); sm += v[j]; }
#pragma unroll
  for (int o = 32; o > 0; o >>= 1) sm += __shfl_xor(sm, o, 64);
  float inv = 1.0f / sm;
  u16v8 ov;
#pragma unroll
  for (int j = 0; j < 8; ++j) ov[j] = f2bf(v[j] * inv);
  *(u16v8*)p = ov;
}

// -------- reduce 8 split-K bf16 slices -> bf16 (per batch 512x512) --------
__global__ __launch_bounds__(256) void reduce8_bf16(const u16* __restrict__ parts,
                                                    u16* __restrict__ out) {
  long i = (((long)blockIdx.x * 256) + threadIdx.x) * 8;  // total 8*262144
  long b = i >> 18;
  long r = i & 262143;
  const u16* p = parts + b * 2097152 + r;
  float acc[8] = {};
#pragma unroll
  for (int s = 0; s < 8; ++s) {
    u16v8 v = *(const u16v8*)(p + (long)s * 262144);
#pragma unroll
    for (int j = 0; j < 8; ++j) acc[j] += bf2f(v[j]);
  }
  u16v8 o;
#pragma unroll
  for (int j = 0; j < 8; ++j) o[j] = f2bf(acc[j]);
  *(u16v8*)(out + i) = o;
}

// ---------------- NT GEMM: C[m,n] = sum_k A[m,k]*B[n,k]  (m97 structure) ----------------
// 128x128 tile, BK=64, 256 threads (4 waves, 2x2), 16x16x32 bf16 MFMA,
// global_load_lds width-16 staging, chunked XCD swizzle, LDS-staged coalesced epilogue.
// MODE: 0 = bf16 store, 1 = f32 store + f32 residual add
template <int MODE>
__global__ __launch_bounds__(256) void gemm_nt(
    const u16* __restrict__ A, const u16* __restrict__ B, void* __restrict__ Cout,
    const float* __restrict__ Res, int K, int lda, int ldb, int ldc,
    long sA, long sB, long sC, long sS, long sRes, int kslices) {
  __shared__ __align__(16) char smem_c[32768];
  u16* As = (u16*)smem_c;
  u16* Bs = (u16*)(smem_c + 16384);

  // chunked XCD swizzle: all tiles of one (batch,slice) land on one XCD
  int gx = gridDim.x, gy = gridDim.y;
  int nwg = gx * gy * (int)gridDim.z;
  int flat = blockIdx.x + gx * (blockIdx.y + gy * blockIdx.z);
  if ((nwg & 7) == 0) { int q = nwg >> 3; flat = (flat & 7) * q + (flat >> 3); }
  int bx = flat % gx; int tmp = flat / gx; int by = tmp % gy; int z = tmp / gy;

  int b = z / kslices;
  int s = z - b * kslices;
  const u16* Ag = A + (long)b * sA + (long)s * K;  // k-offset within rows
  const u16* Bg = B + (long)b * sB + (long)s * K;

  long m0 = (long)bx * 128;
  long n0 = (long)by * 128;

  int tid  = threadIdx.x;
  int lane = tid & 63;
  int wid  = tid >> 6;
  int wm = wid >> 1, wn = wid & 1;

  int srow = wid * 8 + (lane >> 3);   // staging: 8 rows per wave per call
  int scol = (lane & 7) * 8;          // 16B per lane

  f32x4 acc[4][4] = {};

  for (int k0 = 0; k0 < K; k0 += 64) {
#pragma unroll
    for (int c = 0; c < 4; ++c) {
      int row = c * 32 + srow;
      __builtin_amdgcn_global_load_lds(
          (const __attribute__((address_space(1))) void*)(Ag + (m0 + row) * lda + k0 + scol),
          (__attribute__((address_space(3))) void*)(As + (c * 32 + wid * 8) * 64),
          16, 0, 0);
    }
#pragma unroll
    for (int c = 0; c < 4; ++c) {
      int row = c * 32 + srow;
      __builtin_amdgcn_global_load_lds(
          (const __attribute__((address_space(1))) void*)(Bg + (n0 + row) * ldb + k0 + scol),
          (__attribute__((address_space(3))) void*)(Bs + (c * 32 + wid * 8) * 64),
          16, 0, 0);
    }
    __syncthreads();
#pragma unroll
    for (int kk = 0; kk < 2; ++kk) {
      int kofs = kk * 32 + (lane >> 4) * 8;
      bf16x8 af[4], bfr[4];
#pragma unroll
      for (int i = 0; i < 4; ++i) {
        af[i]  = *(const bf16x8*)&As[(wm * 64 + i * 16 + (lane & 15)) * 64 + kofs];
        bfr[i] = *(const bf16x8*)&Bs[(wn * 64 + i * 16 + (lane & 15)) * 64 + kofs];
      }
#pragma unroll
      for (int i = 0; i < 4; ++i)
#pragma unroll
        for (int j = 0; j < 4; ++j)
          acc[i][j] = __builtin_amdgcn_mfma_f32_16x16x32_bf16(af[i], bfr[j], acc[i][j], 0, 0, 0);
    }
    __syncthreads();
  }

  // ---- LDS-staged coalesced epilogue (per-wave private 16x72 f32 region) ----
  float* ep = (float*)(smem_c + wid * 4608);
  long cb  = (long)b * sC + (long)s * sS;
  int row0 = (int)m0 + wm * 64;
  int colb = (int)n0 + wn * 64;
  int lq = lane >> 4;      // 0..3
  int lr = lane & 15;      // 0..15

#pragma unroll
  for (int i = 0; i < 4; ++i) {
    // stage fragment rows into LDS
#pragma unroll
    for (int j = 0; j < 4; ++j)
#pragma unroll
      for (int r = 0; r < 4; ++r)
        ep[(lq * 4 + r) * 72 + lr + j * 16] = acc[i][j][r];
    // read back coalesced (wave-private region: no barrier needed)
#pragma unroll
    for (int p = 0; p < 4; ++p) {
      int rl = p * 4 + lq;
      f32x4 v = *(f32x4*)&ep[rl * 72 + lr * 4];
      long off = (long)(row0 + i * 16 + rl) * ldc + colb + lr * 4;
      if (MODE == 0) {
        u16v4 o;
#pragma unroll
        for (int t = 0; t < 4; ++t) o[t] = f2bf(v[t]);
        *(u16v4*)((u16*)Cout + cb + off) = o;
      } else {
        const float* R = Res + (long)b * sRes;
        f32v4 rv = *(const f32v4*)&R[off];
        f32v4 ov;
#pragma unroll
        for (int t = 0; t < 4; ++t) ov[t] = v[t] + rv[t];
        *(f32v4*)((float*)Cout + cb + off) = ov;
      }
    }
  }
}

// ---------------- host ----------------
extern "C" void kernel_launch(void* const* d_in, const int* in_sizes, int n_in,
                              void* d_out, int out_size, void* d_ws, size_t ws_size,
                              hipStream_t stream) {
  (void)in_sizes; (void)n_in; (void)out_size; (void)ws_size;
  const float* h    = (const float*)d_in[0];
  const float* hret = (const float*)d_in[1];
  const float* Wc   = (const float*)d_in[2];
  const float* Wa   = (const float*)d_in[3];
  const float* Wk   = (const float*)d_in[4];
  const float* Wv   = (const float*)d_in[5];
  const float* Wo   = (const float*)d_in[6];
  float* out = (float*)d_out;
  char*  ws  = (char*)d_ws;

  constexpr long MB = 1024 * 1024;
  // workspace layout (peak 132 MB, overlay-allocated; stream order guarantees liveness)
  u16*   w_cond = (u16*)(ws + 0);
  u16*   w_attn = (u16*)(ws + 786432);
  u16*   w_k    = (u16*)(ws + 1310720);
  u16*   w_v    = (u16*)(ws + 1835008);
  u16*   w_out  = (u16*)(ws + 2359296);
  u16*   w_vT   = (u16*)(ws + 2883584);
  u16*   h_bf   = (u16*)(ws + 4 * MB);    // 32MB  [live: cvt .. XT build]
  u16*   attn   = (u16*)(ws + 36 * MB);   // 32MB  [live: logits .. final]
  u16*   hr_bf  = (u16*)(ws + 68 * MB);   // 16MB  [live: hrGEMM .. XT build]
  u16*   xt     = (u16*)(ws + 84 * MB);   // 48MB  [live: XT build .. Gram]
  u16*   hrin   = (u16*)(ws + 84 * MB);   // 24MB  overlay (dead before xt written)
  u16*   gparts = (u16*)(ws + 4 * MB);    // 32MB  overlay h_bf (dead by then) — bf16 partials
  u16*   g_bf   = (u16*)(ws + 68 * MB);   // 4MB   overlay hr_bf (dead by then)
  u16*   u_mat  = (u16*)(ws + 72 * MB);
  u16*   v1     = (u16*)(ws + 73 * MB);
  u16*   f2t    = (u16*)(ws + 77 * MB);

  // 1) f32 -> bf16 conversions
  cvt_f32_bf16<<<8192, 256, 0, stream>>>(h,    h_bf,  16777216L);
  cvt_f32_bf16<<<6144, 256, 0, stream>>>(hret, hrin,  12582912L);
  cvt_f32_bf16<<<192,  256, 0, stream>>>(Wc,   w_cond,  393216L);
  cvt_f32_bf16<<<128,  256, 0, stream>>>(Wa,   w_attn,  262144L);
  cvt_f32_bf16<<<128,  256, 0, stream>>>(Wk,   w_k,     262144L);
  cvt_f32_bf16<<<128,  256, 0, stream>>>(Wv,   w_v,     262144L);
  cvt_f32_bf16<<<128,  256, 0, stream>>>(Wo,   w_out,   262144L);

  // 2) W_v^T (for U = W_out @ W_v expressed as NT)
  transpose_bf16<<<dim3(8, 8, 1), 256, 0, stream>>>(w_v, w_vT, 512, 512, 0, 0);

  // 3) hr = h_retrieved @ W_cond^T   [16384 x 512, K=768]
  gemm_nt<0><<<dim3(128, 4, 1), 256, 0, stream>>>(hrin, w_cond, hr_bf, nullptr,
      768, 768, 768, 512, 0, 0, 0, 0, 0, 1);

  // 4) logits = h @ W_attn^T  [32768 x 512, K=512], then softmax in place -> attn
  gemm_nt<0><<<dim3(256, 4, 1), 256, 0, stream>>>(h_bf, w_attn, attn, nullptr,
      512, 512, 512, 512, 0, 0, 0, 0, 0, 1);
  softmax512<<<8192, 256, 0, stream>>>(attn);

  // 5) XT[b, d, n] = X[b, n, d],  X = [h ; hr]  (n: 0..4095 = h, 4096..6143 = hr)
  transpose_bf16<<<dim3(64, 8, 8), 256, 0, stream>>>(h_bf,  xt,        512, 6144, 2097152L, 3145728L);
  transpose_bf16<<<dim3(32, 8, 8), 256, 0, stream>>>(hr_bf, xt + 4096, 512, 6144, 1048576L, 3145728L);

  // 6) Gram G = X^T X via NT(XT, XT), split-K=8 into bf16 partials, then reduce -> bf16
  gemm_nt<0><<<dim3(4, 4, 64), 256, 0, stream>>>(xt, xt, gparts, nullptr,
      768, 6144, 6144, 512, 3145728L, 3145728L, 2097152L, 262144L, 0, 8);
  reduce8_bf16<<<1024, 256, 0, stream>>>(gparts, g_bf);

  // 7) f2^T = W_out W_v G W_k^T  (G symmetric):
  //    U = NT(W_out, W_vT) = W_out W_v ;  V1 = NT(U, G) = U G ;  f2T = NT(V1, W_k)
  gemm_nt<0><<<dim3(4, 4, 1), 256, 0, stream>>>(w_out, w_vT, u_mat, nullptr,
      512, 512, 512, 512, 0, 0, 0, 0, 0, 1);
  gemm_nt<0><<<dim3(4, 4, 8), 256, 0, stream>>>(u_mat, g_bf, v1, nullptr,
      512, 512, 512, 512, 0, 262144L, 262144L, 0, 0, 1);
  gemm_nt<0><<<dim3(4, 4, 8), 256, 0, stream>>>(v1, w_k, f2t, nullptr,
      512, 512, 512, 512, 262144L, 0, 262144L, 0, 0, 1);

  // 8) out = h + attn @ f2  via NT(attn, f2T) with fused residual, f32 out
  gemm_nt<1><<<dim3(32, 4, 8), 256, 0, stream>>>(attn, f2t, out, h,
      512, 512, 512, 512, 2097152L, 262144L, 2097152L, 0, 2097152L, 1);
}

// Round 3
// 247.158 us; speedup vs baseline: 1.1065x; 1.1065x over previous
//
#include <hip/hip_runtime.h>
#include <hip/hip_bf16.h>

// Problem: B=8, N=4096, M=2048, IN=512, D=512, CTX=768
// out = h + attn @ f2,  attn = softmax(h W_a^T),  f2^T = W_out W_v G W_k^T,
// G = X^T X (symmetric), X = [h; h_retrieved W_c^T]  (all bf16 MFMA internally)

typedef unsigned short u16;
typedef __bf16 bf16x8 __attribute__((ext_vector_type(8)));
typedef float  f32x4  __attribute__((ext_vector_type(4)));
typedef float  f32v4  __attribute__((ext_vector_type(4)));
typedef u16    u16v4  __attribute__((ext_vector_type(4)));
typedef u16    u16v8  __attribute__((ext_vector_type(8)));

__device__ __forceinline__ u16 f2bf(float f) {
  unsigned u = __builtin_bit_cast(unsigned, f);
  u = u + 0x7FFFu + ((u >> 16) & 1u);   // RNE; inputs are finite
  return (u16)(u >> 16);
}
__device__ __forceinline__ float bf2f(u16 s) {
  return __builtin_bit_cast(float, (unsigned)s << 16);
}

// ---------------- elementwise f32 -> bf16 ----------------
__global__ __launch_bounds__(256) void cvt_f32_bf16(const float* __restrict__ in,
                                                    u16* __restrict__ out, long n) {
  long i = (((long)blockIdx.x * 256) + threadIdx.x) * 8;
  if (i >= n) return;
  f32v4 a = *(const f32v4*)(in + i);
  f32v4 b = *(const f32v4*)(in + i + 4);
  u16v8 o;
  o[0] = f2bf(a[0]); o[1] = f2bf(a[1]); o[2] = f2bf(a[2]); o[3] = f2bf(a[3]);
  o[4] = f2bf(b[0]); o[5] = f2bf(b[1]); o[6] = f2bf(b[2]); o[7] = f2bf(b[3]);
  *(u16v8*)(out + i) = o;
}

// ------- fused f32->bf16 convert + dual write (normal layout + transposed) -------
// src [4096 x 512] f32 per batch; dstN = same layout bf16; dstT [512 x 6144] bf16 (cols 0..4095)
__global__ __launch_bounds__(256) void cvt_dual(const float* __restrict__ src,
                                                u16* __restrict__ dstN,
                                                u16* __restrict__ dstT,
                                                long src_bs, long dstT_bs) {
  __shared__ u16 tile[64][72];
  long bz = blockIdx.z;
  const float* S = src + bz * src_bs;
  u16* DN = dstN + bz * src_bs;
  u16* DT = dstT + bz * dstT_bs;
  int r0 = blockIdx.x * 64;   // n-dim tile
  int c0 = blockIdx.y * 64;   // d-dim tile
  int t  = threadIdx.x;
  int tr = t >> 2;            // 0..63
  int tc = (t & 3) * 16;      // 0,16,32,48
  const float* sp = &S[(long)(r0 + tr) * 512 + c0 + tc];
#pragma unroll
  for (int q = 0; q < 2; ++q) {
    f32v4 a = *(const f32v4*)(sp + q * 8);
    f32v4 b = *(const f32v4*)(sp + q * 8 + 4);
    u16v8 o;
    o[0] = f2bf(a[0]); o[1] = f2bf(a[1]); o[2] = f2bf(a[2]); o[3] = f2bf(a[3]);
    o[4] = f2bf(b[0]); o[5] = f2bf(b[1]); o[6] = f2bf(b[2]); o[7] = f2bf(b[3]);
    *(u16v8*)&DN[(long)(r0 + tr) * 512 + c0 + tc + q * 8] = o;
    *(u16v8*)&tile[tr][tc + q * 8] = o;
  }
  __syncthreads();
  int tr2 = t >> 3;           // 0..31
  int tc2 = (t & 7) * 8;
#pragma unroll
  for (int it = 0; it < 2; ++it) {
    int cr = it * 32 + tr2;
    u16v8 o;
#pragma unroll
    for (int j = 0; j < 8; ++j) o[j] = tile[tc2 + j][cr];
    *(u16v8*)&DT[(long)(c0 + cr) * 6144 + r0 + tc2] = o;
  }
}

// ---------------- tiled bf16 transpose: dst[c,r] = src[r,c] ----------------
__global__ __launch_bounds__(256) void transpose_bf16(const u16* __restrict__ src,
                                                      u16* __restrict__ dst,
                                                      int src_ld, int dst_ld,
                                                      long src_bs, long dst_bs) {
  __shared__ u16 tile[64][72];
  long b = blockIdx.z;
  const u16* S = src + b * src_bs;
  u16* D = dst + b * dst_bs;
  int r0 = blockIdx.x * 64;
  int c0 = blockIdx.y * 64;
  int t  = threadIdx.x;
  int tr = t >> 3;
  int tc = (t & 7) * 8;
#pragma unroll
  for (int it = 0; it < 2; ++it) {
    int rr = it * 32 + tr;
    *(u16v8*)&tile[rr][tc] = *(const u16v8*)&S[(long)(r0 + rr) * src_ld + c0 + tc];
  }
  __syncthreads();
#pragma unroll
  for (int it = 0; it < 2; ++it) {
    int cr = it * 32 + tr;
    u16v8 o;
#pragma unroll
    for (int j = 0; j < 8; ++j) o[j] = tile[tc + j][cr];
    *(u16v8*)&D[(long)(c0 + cr) * dst_ld + r0 + tc] = o;
  }
}

// ---------------- row softmax over 512 bf16 (in place), 1 wave/row ----------------
__global__ __launch_bounds__(256) void softmax512(u16* __restrict__ data) {
  long row = (long)blockIdx.x * 4 + (threadIdx.x >> 6);
  int lane = threadIdx.x & 63;
  u16* p = data + row * 512 + lane * 8;
  u16v8 raw = *(const u16v8*)p;
  float v[8];
  float mx = -3.0e38f;
#pragma unroll
  for (int j = 0; j < 8; ++j) { v[j] = bf2f(raw[j]); mx = fmaxf(mx, v[j]); }
#pragma unroll
  for (int o = 32; o > 0; o >>= 1) mx = fmaxf(mx, __shfl_xor(mx, o, 64));
  float sm = 0.f;
#pragma unroll
  for (int j = 0; j < 8; ++j) { v[j] = __expf(v[j] - mx); sm += v[j]; }
#pragma unroll
  for (int o = 32; o > 0; o >>= 1) sm += __shfl_xor(sm, o, 64);
  float inv = 1.0f / sm;
  u16v8 ov;
#pragma unroll
  for (int j = 0; j < 8; ++j) ov[j] = f2bf(v[j] * inv);
  *(u16v8*)p = ov;
}

// -------- reduce 8 split-K bf16 slices -> bf16 (per batch 512x512) --------
__global__ __launch_bounds__(256) void reduce8_bf16(const u16* __restrict__ parts,
                                                    u16* __restrict__ out) {
  long i = (((long)blockIdx.x * 256) + threadIdx.x) * 8;
  long b = i >> 18;
  long r = i & 262143;
  const u16* p = parts + b * 2097152 + r;
  float acc[8] = {};
#pragma unroll
  for (int s = 0; s < 8; ++s) {
    u16v8 v = *(const u16v8*)(p + (long)s * 262144);
#pragma unroll
    for (int j = 0; j < 8; ++j) acc[j] += bf2f(v[j]);
  }
  u16v8 o;
#pragma unroll
  for (int j = 0; j < 8; ++j) o[j] = f2bf(acc[j]);
  *(u16v8*)(out + i) = o;
}

// ---------------- NT GEMM 128x128 (m97 structure) — used for Gram only ----------------
template <int MODE>
__global__ __launch_bounds__(256) void gemm_nt(
    const u16* __restrict__ A, const u16* __restrict__ B, void* __restrict__ Cout,
    const float* __restrict__ Res, int K, int lda, int ldb, int ldc,
    long sA, long sB, long sC, long sS, long sRes, int kslices) {
  __shared__ __align__(16) char smem_c[32768];
  u16* As = (u16*)smem_c;
  u16* Bs = (u16*)(smem_c + 16384);

  int gx = gridDim.x, gy = gridDim.y;
  int nwg = gx * gy * (int)gridDim.z;
  int flat = blockIdx.x + gx * (blockIdx.y + gy * blockIdx.z);
  if ((nwg & 7) == 0) { int q = nwg >> 3; flat = (flat & 7) * q + (flat >> 3); }
  int bx = flat % gx; int tmp = flat / gx; int by = tmp % gy; int z = tmp / gy;

  int b = z / kslices;
  int s = z - b * kslices;
  const u16* Ag = A + (long)b * sA + (long)s * K;
  const u16* Bg = B + (long)b * sB + (long)s * K;

  long m0 = (long)bx * 128;
  long n0 = (long)by * 128;

  int tid  = threadIdx.x;
  int lane = tid & 63;
  int wid  = tid >> 6;
  int wm = wid >> 1, wn = wid & 1;

  int srow = wid * 8 + (lane >> 3);
  int scol = (lane & 7) * 8;

  f32x4 acc[4][4] = {};

  for (int k0 = 0; k0 < K; k0 += 64) {
#pragma unroll
    for (int c = 0; c < 4; ++c) {
      int row = c * 32 + srow;
      __builtin_amdgcn_global_load_lds(
          (const __attribute__((address_space(1))) void*)(Ag + (m0 + row) * lda + k0 + scol),
          (__attribute__((address_space(3))) void*)(As + (c * 32 + wid * 8) * 64),
          16, 0, 0);
    }
#pragma unroll
    for (int c = 0; c < 4; ++c) {
      int row = c * 32 + srow;
      __builtin_amdgcn_global_load_lds(
          (const __attribute__((address_space(1))) void*)(Bg + (n0 + row) * ldb + k0 + scol),
          (__attribute__((address_space(3))) void*)(Bs + (c * 32 + wid * 8) * 64),
          16, 0, 0);
    }
    __syncthreads();
#pragma unroll
    for (int kk = 0; kk < 2; ++kk) {
      int kofs = kk * 32 + (lane >> 4) * 8;
      bf16x8 af[4], bfr[4];
#pragma unroll
      for (int i = 0; i < 4; ++i) {
        af[i]  = *(const bf16x8*)&As[(wm * 64 + i * 16 + (lane & 15)) * 64 + kofs];
        bfr[i] = *(const bf16x8*)&Bs[(wn * 64 + i * 16 + (lane & 15)) * 64 + kofs];
      }
#pragma unroll
      for (int i = 0; i < 4; ++i)
#pragma unroll
        for (int j = 0; j < 4; ++j)
          acc[i][j] = __builtin_amdgcn_mfma_f32_16x16x32_bf16(af[i], bfr[j], acc[i][j], 0, 0, 0);
    }
    __syncthreads();
  }

  float* ep = (float*)(smem_c + wid * 4608);
  long cb  = (long)b * sC + (long)s * sS;
  int row0 = (int)m0 + wm * 64;
  int colb = (int)n0 + wn * 64;
  int lq = lane >> 4;
  int lr = lane & 15;

#pragma unroll
  for (int i = 0; i < 4; ++i) {
#pragma unroll
    for (int j = 0; j < 4; ++j)
#pragma unroll
      for (int r = 0; r < 4; ++r)
        ep[(lq * 4 + r) * 72 + lr + j * 16] = acc[i][j][r];
#pragma unroll
    for (int p = 0; p < 4; ++p) {
      int rl = p * 4 + lq;
      f32x4 v = *(f32x4*)&ep[rl * 72 + lr * 4];
      long off = (long)(row0 + i * 16 + rl) * ldc + colb + lr * 4;
      if (MODE == 0) {
        u16v4 o;
#pragma unroll
        for (int t = 0; t < 4; ++t) o[t] = f2bf(v[t]);
        *(u16v4*)((u16*)Cout + cb + off) = o;
      } else {
        const float* R = Res + (long)b * sRes;
        f32v4 rv = *(const f32v4*)&R[off];
        f32v4 ov;
#pragma unroll
        for (int t = 0; t < 4; ++t) ov[t] = v[t] + rv[t];
        *(f32v4*)((float*)Cout + cb + off) = ov;
      }
    }
  }
}

// ---------------- NT GEMM 64x128 skinny-K streaming variant ----------------
// grid.x = N tiles (128 wide), grid.y = M tiles (64 tall), grid.z = batch.
// 4 waves 2x2: wave tile 32x64. acc = 2x4 frags (32 VGPR). LDS 24KB -> 6 blocks/CU.
// MODE: 0 = bf16 store, 1 = f32 store + f32 residual, 3 = bf16 TRANSPOSED store
template <int MODE>
__global__ __launch_bounds__(256) void gemm64(
    const u16* __restrict__ A, const u16* __restrict__ B, void* __restrict__ Cout,
    const float* __restrict__ Res, int K, int lda, int ldb, int ldc,
    long sA, long sB, long sC, long sRes) {
  __shared__ __align__(16) char smem_c[24576];
  u16* As = (u16*)smem_c;              // 64 x 64
  u16* Bs = (u16*)(smem_c + 8192);     // 128 x 64

  int gx = gridDim.x, gy = gridDim.y;
  int nwg = gx * gy * (int)gridDim.z;
  int flat = blockIdx.x + gx * (blockIdx.y + gy * blockIdx.z);
  if ((nwg & 7) == 0) { int q = nwg >> 3; flat = (flat & 7) * q + (flat >> 3); }
  int bx = flat % gx; int tmp = flat / gx; int by = tmp % gy; int b = tmp / gy;

  long n0 = (long)bx * 128;
  long m0 = (long)by * 64;
  const u16* Ag = A + (long)b * sA;
  const u16* Bg = B + (long)b * sB;

  int tid  = threadIdx.x;
  int lane = tid & 63;
  int wid  = tid >> 6;
  int wm = wid >> 1, wn = wid & 1;

  int srow = wid * 8 + (lane >> 3);   // 0..31
  int scol = (lane & 7) * 8;

  f32x4 acc[2][4] = {};

  for (int k0 = 0; k0 < K; k0 += 64) {
#pragma unroll
    for (int c = 0; c < 2; ++c) {
      int row = c * 32 + srow;
      __builtin_amdgcn_global_load_lds(
          (const __attribute__((address_space(1))) void*)(Ag + (m0 + row) * lda + k0 + scol),
          (__attribute__((address_space(3))) void*)(As + (c * 32 + wid * 8) * 64),
          16, 0, 0);
    }
#pragma unroll
    for (int c = 0; c < 4; ++c) {
      int row = c * 32 + srow;
      __builtin_amdgcn_global_load_lds(
          (const __attribute__((address_space(1))) void*)(Bg + (n0 + row) * ldb + k0 + scol),
          (__attribute__((address_space(3))) void*)(Bs + (c * 32 + wid * 8) * 64),
          16, 0, 0);
    }
    __syncthreads();
#pragma unroll
    for (int kk = 0; kk < 2; ++kk) {
      int kofs = kk * 32 + (lane >> 4) * 8;
      bf16x8 af[2], bfr[4];
#pragma unroll
      for (int i = 0; i < 2; ++i)
        af[i]  = *(const bf16x8*)&As[(wm * 32 + i * 16 + (lane & 15)) * 64 + kofs];
#pragma unroll
      for (int j = 0; j < 4; ++j)
        bfr[j] = *(const bf16x8*)&Bs[(wn * 64 + j * 16 + (lane & 15)) * 64 + kofs];
#pragma unroll
      for (int i = 0; i < 2; ++i)
#pragma unroll
        for (int j = 0; j < 4; ++j)
          acc[i][j] = __builtin_amdgcn_mfma_f32_16x16x32_bf16(af[i], bfr[j], acc[i][j], 0, 0, 0);
    }
    __syncthreads();
  }

  int lq = lane >> 4;
  int lr = lane & 15;

  if (MODE == 0 || MODE == 1) {
    float* ep = (float*)(smem_c + wid * 4608);   // wave-private, no barrier needed
    long cb  = (long)b * sC;
    int row0 = (int)m0 + wm * 32;
    int colb = (int)n0 + wn * 64;
#pragma unroll
    for (int i = 0; i < 2; ++i) {
#pragma unroll
      for (int j = 0; j < 4; ++j)
#pragma unroll
        for (int r = 0; r < 4; ++r)
          ep[(lq * 4 + r) * 72 + lr + j * 16] = acc[i][j][r];
#pragma unroll
      for (int p = 0; p < 4; ++p) {
        int rl = p * 4 + lq;
        f32x4 v = *(f32x4*)&ep[rl * 72 + lr * 4];
        long off = (long)(row0 + i * 16 + rl) * ldc + colb + lr * 4;
        if (MODE == 0) {
          u16v4 o;
#pragma unroll
          for (int t = 0; t < 4; ++t) o[t] = f2bf(v[t]);
          *(u16v4*)((u16*)Cout + cb + off) = o;
        } else {
          const float* R = Res + (long)b * sRes;
          f32v4 rv = *(const f32v4*)&R[off];
          f32v4 ov;
#pragma unroll
          for (int t = 0; t < 4; ++t) ov[t] = v[t] + rv[t];
          *(f32v4*)((float*)Cout + cb + off) = ov;
        }
      }
    }
  } else {
    // MODE 3: transposed bf16 store. Stage full 64x128 tile as CT[128][64] in LDS,
    // then write 128 rows of 64 contiguous u16 (coalesced 128B segments).
    u16* tT = (u16*)smem_c;   // [128][72] u16 = 18432 B
#pragma unroll
    for (int i = 0; i < 2; ++i)
#pragma unroll
      for (int j = 0; j < 4; ++j)
#pragma unroll
        for (int r = 0; r < 4; ++r)
          tT[(wn * 64 + j * 16 + lr) * 72 + wm * 32 + i * 16 + lq * 4 + r] = f2bf(acc[i][j][r]);
    __syncthreads();
    long cb = (long)b * sC;
    int ct  = tid >> 1;          // 0..127 : row of CT (col of C)
    int seg = (tid & 1) * 32;    // half of the 64 m-values
    u16* dst = (u16*)Cout + cb + (long)(n0 + ct) * ldc + m0 + seg;
    const u16* srcl = &tT[ct * 72 + seg];
#pragma unroll
    for (int q = 0; q < 4; ++q)
      *(u16v8*)(dst + q * 8) = *(const u16v8*)(srcl + q * 8);
  }
}

// ---------------- host ----------------
extern "C" void kernel_launch(void* const* d_in, const int* in_sizes, int n_in,
                              void* d_out, int out_size, void* d_ws, size_t ws_size,
                              hipStream_t stream) {
  (void)in_sizes; (void)n_in; (void)out_size; (void)ws_size;
  const float* h    = (const float*)d_in[0];
  const float* hret = (const float*)d_in[1];
  const float* Wc   = (const float*)d_in[2];
  const float* Wa   = (const float*)d_in[3];
  const float* Wk   = (const float*)d_in[4];
  const float* Wv   = (const float*)d_in[5];
  const float* Wo   = (const float*)d_in[6];
  float* out = (float*)d_out;
  char*  ws  = (char*)d_ws;

  constexpr long MB = 1024 * 1024;
  // workspace layout (peak 132 MB):
  //  0.. 4MB : weights (bf16) + w_vT
  //  4..36MB : h_bf (live: cvt_dual .. logits) / gparts (live: Gram .. reduce8)
  // 36..68MB : hrin (live: cvt .. hr GEMM) / attn (live: logits .. final)
  // 68..84MB : g_bf(4) u_mat(1) v1(4) f2t(4)
  // 84..132MB: xt (live: cvt_dual .. Gram)
  u16*   w_cond = (u16*)(ws + 0);
  u16*   w_attn = (u16*)(ws + 786432);
  u16*   w_k    = (u16*)(ws + 1310720);
  u16*   w_v    = (u16*)(ws + 1835008);
  u16*   w_out  = (u16*)(ws + 2359296);
  u16*   w_vT   = (u16*)(ws + 2883584);
  u16*   h_bf   = (u16*)(ws + 4 * MB);
  u16*   gparts = (u16*)(ws + 4 * MB);    // overlay h_bf (dead after logits)
  u16*   hrin   = (u16*)(ws + 36 * MB);
  u16*   attn   = (u16*)(ws + 36 * MB);   // overlay hrin (dead after hr GEMM)
  u16*   g_bf   = (u16*)(ws + 68 * MB);
  u16*   u_mat  = (u16*)(ws + 72 * MB);
  u16*   v1     = (u16*)(ws + 73 * MB);
  u16*   f2t    = (u16*)(ws + 77 * MB);
  u16*   xt     = (u16*)(ws + 84 * MB);

  // 1) h: fused convert + transpose  (h_bf rows + xt[:, 0:4096])
  cvt_dual<<<dim3(64, 8, 8), 256, 0, stream>>>(h, h_bf, xt, 2097152L, 3145728L);
  // 2) h_retrieved -> bf16
  cvt_f32_bf16<<<6144, 256, 0, stream>>>(hret, hrin, 12582912L);
  // 3) weights -> bf16
  cvt_f32_bf16<<<192, 256, 0, stream>>>(Wc, w_cond, 393216L);
  cvt_f32_bf16<<<128, 256, 0, stream>>>(Wa, w_attn, 262144L);
  cvt_f32_bf16<<<128, 256, 0, stream>>>(Wk, w_k,    262144L);
  cvt_f32_bf16<<<128, 256, 0, stream>>>(Wv, w_v,    262144L);
  cvt_f32_bf16<<<128, 256, 0, stream>>>(Wo, w_out,  262144L);
  transpose_bf16<<<dim3(8, 8, 1), 256, 0, stream>>>(w_v, w_vT, 512, 512, 0, 0);

  // 4) hr = hrin @ W_cond^T, written TRANSPOSED into xt[:, 4096:6144]
  gemm64<3><<<dim3(4, 32, 8), 256, 0, stream>>>(hrin, w_cond, xt + 4096, nullptr,
      768, 768, 768, 6144, 1572864L, 0, 3145728L, 0);

  // 5) logits = h @ W_attn^T (treat all batches as M=32768), softmax in place
  gemm64<0><<<dim3(4, 512, 1), 256, 0, stream>>>(h_bf, w_attn, attn, nullptr,
      512, 512, 512, 512, 0, 0, 0, 0);
  softmax512<<<8192, 256, 0, stream>>>(attn);

  // 6) Gram G = X^T X via NT(xt, xt), split-K=8 bf16 partials, reduce -> bf16
  gemm_nt<0><<<dim3(4, 4, 64), 256, 0, stream>>>(xt, xt, gparts, nullptr,
      768, 6144, 6144, 512, 3145728L, 3145728L, 2097152L, 262144L, 0, 8);
  reduce8_bf16<<<1024, 256, 0, stream>>>(gparts, g_bf);

  // 7) f2^T = W_out W_v G W_k^T (G symmetric):
  gemm64<0><<<dim3(4, 8, 1), 256, 0, stream>>>(w_out, w_vT, u_mat, nullptr,
      512, 512, 512, 512, 0, 0, 0, 0);
  gemm64<0><<<dim3(4, 8, 8), 256, 0, stream>>>(u_mat, g_bf, v1, nullptr,
      512, 512, 512, 512, 0, 262144L, 262144L, 0);
  gemm64<0><<<dim3(4, 8, 8), 256, 0, stream>>>(v1, w_k, f2t, nullptr,
      512, 512, 512, 512, 262144L, 0, 262144L, 0);

  // 8) out = h + attn @ f2  (fused residual, f32 out)
  gemm64<1><<<dim3(4, 64, 8), 256, 0, stream>>>(attn, f2t, out, h,
      512, 512, 512, 512, 2097152L, 262144L, 2097152L, 2097152L);
}

// Round 4
// 226.458 us; speedup vs baseline: 1.2077x; 1.0914x over previous
//
#include <hip/hip_runtime.h>
#include <hip/hip_bf16.h>

// Problem: B=8, N=4096, M=2048, IN=512, D=512, CTX=768
// out = h + attn @ f2,  attn = softmax(h W_a^T),  f2^T = W_out W_v G W_k^T,
// G = X^T X (symmetric), X = [h; h_retrieved W_c^T]  (all bf16 MFMA internally)

typedef unsigned short u16;
typedef __bf16 bf16x8 __attribute__((ext_vector_type(8)));
typedef float  f32x4  __attribute__((ext_vector_type(4)));
typedef float  f32v4  __attribute__((ext_vector_type(4)));
typedef u16    u16v4  __attribute__((ext_vector_type(4)));
typedef u16    u16v8  __attribute__((ext_vector_type(8)));

__device__ __forceinline__ u16 f2bf(float f) {
  unsigned u = __builtin_bit_cast(unsigned, f);
  u = u + 0x7FFFu + ((u >> 16) & 1u);   // RNE; inputs are finite
  return (u16)(u >> 16);
}
__device__ __forceinline__ float bf2f(u16 s) {
  return __builtin_bit_cast(float, (unsigned)s << 16);
}

// ------- fused f32->bf16 convert + dual write (normal layout + transposed) -------
// src [4096 x 512] f32 per batch; dstN = same layout bf16; dstT [512 x 6144] bf16 (cols 0..4095)
__global__ __launch_bounds__(256) void cvt_dual(const float* __restrict__ src,
                                                u16* __restrict__ dstN,
                                                u16* __restrict__ dstT,
                                                long src_bs, long dstT_bs) {
  __shared__ u16 tile[64][72];
  long bz = blockIdx.z;
  const float* S = src + bz * src_bs;
  u16* DN = dstN + bz * src_bs;
  u16* DT = dstT + bz * dstT_bs;
  int r0 = blockIdx.x * 64;   // n-dim tile
  int c0 = blockIdx.y * 64;   // d-dim tile
  int t  = threadIdx.x;
  int tr = t >> 2;            // 0..63
  int tc = (t & 3) * 16;      // 0,16,32,48
  const float* sp = &S[(long)(r0 + tr) * 512 + c0 + tc];
#pragma unroll
  for (int q = 0; q < 2; ++q) {
    f32v4 a = *(const f32v4*)(sp + q * 8);
    f32v4 b = *(const f32v4*)(sp + q * 8 + 4);
    u16v8 o;
    o[0] = f2bf(a[0]); o[1] = f2bf(a[1]); o[2] = f2bf(a[2]); o[3] = f2bf(a[3]);
    o[4] = f2bf(b[0]); o[5] = f2bf(b[1]); o[6] = f2bf(b[2]); o[7] = f2bf(b[3]);
    *(u16v8*)&DN[(long)(r0 + tr) * 512 + c0 + tc + q * 8] = o;
    *(u16v8*)&tile[tr][tc + q * 8] = o;
  }
  __syncthreads();
  int tr2 = t >> 3;           // 0..31
  int tc2 = (t & 7) * 8;
#pragma unroll
  for (int it = 0; it < 2; ++it) {
    int cr = it * 32 + tr2;
    u16v8 o;
#pragma unroll
    for (int j = 0; j < 8; ++j) o[j] = tile[tc2 + j][cr];
    *(u16v8*)&DT[(long)(c0 + cr) * 6144 + r0 + tc2] = o;
  }
}

// ------- all weight prep in ONE dispatch: 4 converts + Wv dual (normal + transposed) -------
// blocks 0..191: Wc, 192..319: Wa, 320..447: Wk, 448..575: Wo, 576..639: Wv dual 64x64 tiles
__global__ __launch_bounds__(256) void prep_weights(
    const float* __restrict__ Wc, const float* __restrict__ Wa,
    const float* __restrict__ Wk, const float* __restrict__ Wv,
    const float* __restrict__ Wo,
    u16* __restrict__ wc, u16* __restrict__ wa, u16* __restrict__ wk,
    u16* __restrict__ wv, u16* __restrict__ wvT, u16* __restrict__ wo) {
  __shared__ u16 tile[64][72];
  int bx = blockIdx.x;
  int t = threadIdx.x;
  if (bx < 576) {
    const float* src; u16* dst; long base;
    if (bx < 192)      { src = Wc; dst = wc; base = (long)bx * 2048; }
    else if (bx < 320) { src = Wa; dst = wa; base = (long)(bx - 192) * 2048; }
    else if (bx < 448) { src = Wk; dst = wk; base = (long)(bx - 320) * 2048; }
    else               { src = Wo; dst = wo; base = (long)(bx - 448) * 2048; }
    long i = base + (long)t * 8;
    f32v4 a = *(const f32v4*)(src + i);
    f32v4 b = *(const f32v4*)(src + i + 4);
    u16v8 o;
    o[0] = f2bf(a[0]); o[1] = f2bf(a[1]); o[2] = f2bf(a[2]); o[3] = f2bf(a[3]);
    o[4] = f2bf(b[0]); o[5] = f2bf(b[1]); o[6] = f2bf(b[2]); o[7] = f2bf(b[3]);
    *(u16v8*)(dst + i) = o;
  } else {
    int b2 = bx - 576;
    int r0 = (b2 >> 3) * 64, c0 = (b2 & 7) * 64;
    int tr = t >> 2, tc = (t & 3) * 16;
    const float* sp = &Wv[(long)(r0 + tr) * 512 + c0 + tc];
#pragma unroll
    for (int q = 0; q < 2; ++q) {
      f32v4 a = *(const f32v4*)(sp + q * 8);
      f32v4 b = *(const f32v4*)(sp + q * 8 + 4);
      u16v8 o;
      o[0] = f2bf(a[0]); o[1] = f2bf(a[1]); o[2] = f2bf(a[2]); o[3] = f2bf(a[3]);
      o[4] = f2bf(b[0]); o[5] = f2bf(b[1]); o[6] = f2bf(b[2]); o[7] = f2bf(b[3]);
      *(u16v8*)&wv[(long)(r0 + tr) * 512 + c0 + tc + q * 8] = o;
      *(u16v8*)&tile[tr][tc + q * 8] = o;
    }
    __syncthreads();
    int tr2 = t >> 3, tc2 = (t & 7) * 8;
#pragma unroll
    for (int it = 0; it < 2; ++it) {
      int cr = it * 32 + tr2;
      u16v8 o;
#pragma unroll
      for (int j = 0; j < 8; ++j) o[j] = tile[tc2 + j][cr];
      *(u16v8*)&wvT[(long)(c0 + cr) * 512 + r0 + tc2] = o;
    }
  }
}

// -------- reduce 8 split-K bf16 slices -> bf16 (per batch 512x512) --------
__global__ __launch_bounds__(256) void reduce8_bf16(const u16* __restrict__ parts,
                                                    u16* __restrict__ out) {
  long i = (((long)blockIdx.x * 256) + threadIdx.x) * 8;
  long b = i >> 18;
  long r = i & 262143;
  const u16* p = parts + b * 2097152 + r;
  float acc[8] = {};
#pragma unroll
  for (int s = 0; s < 8; ++s) {
    u16v8 v = *(const u16v8*)(p + (long)s * 262144);
#pragma unroll
    for (int j = 0; j < 8; ++j) acc[j] += bf2f(v[j]);
  }
  u16v8 o;
#pragma unroll
  for (int j = 0; j < 8; ++j) o[j] = f2bf(acc[j]);
  *(u16v8*)(out + i) = o;
}

// ---------------- NT GEMM 128x128 (m97 structure) — used for Gram only ----------------
template <int MODE>
__global__ __launch_bounds__(256) void gemm_nt(
    const u16* __restrict__ A, const u16* __restrict__ B, void* __restrict__ Cout,
    const float* __restrict__ Res, int K, int lda, int ldb, int ldc,
    long sA, long sB, long sC, long sS, long sRes, int kslices) {
  __shared__ __align__(16) char smem_c[32768];
  u16* As = (u16*)smem_c;
  u16* Bs = (u16*)(smem_c + 16384);

  int gx = gridDim.x, gy = gridDim.y;
  int nwg = gx * gy * (int)gridDim.z;
  int flat = blockIdx.x + gx * (blockIdx.y + gy * blockIdx.z);
  if ((nwg & 7) == 0) { int q = nwg >> 3; flat = (flat & 7) * q + (flat >> 3); }
  int bx = flat % gx; int tmp = flat / gx; int by = tmp % gy; int z = tmp / gy;

  int b = z / kslices;
  int s = z - b * kslices;
  const u16* Ag = A + (long)b * sA + (long)s * K;
  const u16* Bg = B + (long)b * sB + (long)s * K;

  long m0 = (long)bx * 128;
  long n0 = (long)by * 128;

  int tid  = threadIdx.x;
  int lane = tid & 63;
  int wid  = tid >> 6;
  int wm = wid >> 1, wn = wid & 1;

  int srow = wid * 8 + (lane >> 3);
  int scol = (lane & 7) * 8;

  f32x4 acc[4][4] = {};

  for (int k0 = 0; k0 < K; k0 += 64) {
#pragma unroll
    for (int c = 0; c < 4; ++c) {
      int row = c * 32 + srow;
      __builtin_amdgcn_global_load_lds(
          (const __attribute__((address_space(1))) void*)(Ag + (m0 + row) * lda + k0 + scol),
          (__attribute__((address_space(3))) void*)(As + (c * 32 + wid * 8) * 64),
          16, 0, 0);
    }
#pragma unroll
    for (int c = 0; c < 4; ++c) {
      int row = c * 32 + srow;
      __builtin_amdgcn_global_load_lds(
          (const __attribute__((address_space(1))) void*)(Bg + (n0 + row) * ldb + k0 + scol),
          (__attribute__((address_space(3))) void*)(Bs + (c * 32 + wid * 8) * 64),
          16, 0, 0);
    }
    __syncthreads();
#pragma unroll
    for (int kk = 0; kk < 2; ++kk) {
      int kofs = kk * 32 + (lane >> 4) * 8;
      bf16x8 af[4], bfr[4];
#pragma unroll
      for (int i = 0; i < 4; ++i) {
        af[i]  = *(const bf16x8*)&As[(wm * 64 + i * 16 + (lane & 15)) * 64 + kofs];
        bfr[i] = *(const bf16x8*)&Bs[(wn * 64 + i * 16 + (lane & 15)) * 64 + kofs];
      }
#pragma unroll
      for (int i = 0; i < 4; ++i)
#pragma unroll
        for (int j = 0; j < 4; ++j)
          acc[i][j] = __builtin_amdgcn_mfma_f32_16x16x32_bf16(af[i], bfr[j], acc[i][j], 0, 0, 0);
    }
    __syncthreads();
  }

  float* ep = (float*)(smem_c + wid * 4608);
  long cb  = (long)b * sC + (long)s * sS;
  int row0 = (int)m0 + wm * 64;
  int colb = (int)n0 + wn * 64;
  int lq = lane >> 4;
  int lr = lane & 15;

#pragma unroll
  for (int i = 0; i < 4; ++i) {
#pragma unroll
    for (int j = 0; j < 4; ++j)
#pragma unroll
      for (int r = 0; r < 4; ++r)
        ep[(lq * 4 + r) * 72 + lr + j * 16] = acc[i][j][r];
#pragma unroll
    for (int p = 0; p < 4; ++p) {
      int rl = p * 4 + lq;
      f32x4 v = *(f32x4*)&ep[rl * 72 + lr * 4];
      long off = (long)(row0 + i * 16 + rl) * ldc + colb + lr * 4;
      if (MODE == 0) {
        u16v4 o;
#pragma unroll
        for (int t = 0; t < 4; ++t) o[t] = f2bf(v[t]);
        *(u16v4*)((u16*)Cout + cb + off) = o;
      } else {
        const float* R = Res + (long)b * sRes;
        f32v4 rv = *(const f32v4*)&R[off];
        f32v4 ov;
#pragma unroll
        for (int t = 0; t < 4; ++t) ov[t] = v[t] + rv[t];
        *(f32v4*)((float*)Cout + cb + off) = ov;
      }
    }
  }
}

// ---------------- NT GEMM 64x128 skinny-K streaming variant ----------------
// grid.x = N tiles (128 wide), grid.y = M tiles (64 tall), grid.z = batch.
// MODE: 0 = bf16 store, 1 = f32 store + f32 residual, 3 = bf16 TRANSPOSED store
// AF32: A operand is f32 in global, reg-staged with on-the-fly bf16 convert.
template <int MODE, bool AF32>
__global__ __launch_bounds__(256) void gemm64(
    const void* __restrict__ Ap, const u16* __restrict__ B, void* __restrict__ Cout,
    const float* __restrict__ Res, int K, int lda, int ldb, int ldc,
    long sA, long sB, long sC, long sRes) {
  __shared__ __align__(16) char smem_c[24576];
  u16* As = (u16*)smem_c;              // 64 x 64
  u16* Bs = (u16*)(smem_c + 8192);     // 128 x 64

  int gx = gridDim.x, gy = gridDim.y;
  int nwg = gx * gy * (int)gridDim.z;
  int flat = blockIdx.x + gx * (blockIdx.y + gy * blockIdx.z);
  if ((nwg & 7) == 0) { int q = nwg >> 3; flat = (flat & 7) * q + (flat >> 3); }
  int bx = flat % gx; int tmp = flat / gx; int by = tmp % gy; int b = tmp / gy;

  long n0 = (long)bx * 128;
  long m0 = (long)by * 64;
  const u16* Ag = (const u16*)Ap + (long)b * sA;     // bf16 path
  const float* Af = (const float*)Ap + (long)b * sA; // f32 path
  const u16* Bg = B + (long)b * sB;

  int tid  = threadIdx.x;
  int lane = tid & 63;
  int wid  = tid >> 6;
  int wm = wid >> 1, wn = wid & 1;

  int srow = wid * 8 + (lane >> 3);   // 0..31
  int scol = (lane & 7) * 8;

  f32x4 acc[2][4] = {};

  for (int k0 = 0; k0 < K; k0 += 64) {
    if constexpr (AF32) {
      int arow = tid >> 2;            // 0..63
      int acol = (tid & 3) * 16;      // 0,16,32,48
      const float* sp = Af + (m0 + arow) * (long)lda + k0 + acol;
      f32v4 x0 = *(const f32v4*)sp;
      f32v4 x1 = *(const f32v4*)(sp + 4);
      f32v4 x2 = *(const f32v4*)(sp + 8);
      f32v4 x3 = *(const f32v4*)(sp + 12);
      u16v8 o0, o1;
      o0[0] = f2bf(x0[0]); o0[1] = f2bf(x0[1]); o0[2] = f2bf(x0[2]); o0[3] = f2bf(x0[3]);
      o0[4] = f2bf(x1[0]); o0[5] = f2bf(x1[1]); o0[6] = f2bf(x1[2]); o0[7] = f2bf(x1[3]);
      o1[0] = f2bf(x2[0]); o1[1] = f2bf(x2[1]); o1[2] = f2bf(x2[2]); o1[3] = f2bf(x2[3]);
      o1[4] = f2bf(x3[0]); o1[5] = f2bf(x3[1]); o1[6] = f2bf(x3[2]); o1[7] = f2bf(x3[3]);
      *(u16v8*)&As[arow * 64 + acol] = o0;
      *(u16v8*)&As[arow * 64 + acol + 8] = o1;
    } else {
#pragma unroll
      for (int c = 0; c < 2; ++c) {
        int row = c * 32 + srow;
        __builtin_amdgcn_global_load_lds(
            (const __attribute__((address_space(1))) void*)(Ag + (m0 + row) * lda + k0 + scol),
            (__attribute__((address_space(3))) void*)(As + (c * 32 + wid * 8) * 64),
            16, 0, 0);
      }
    }
#pragma unroll
    for (int c = 0; c < 4; ++c) {
      int row = c * 32 + srow;
      __builtin_amdgcn_global_load_lds(
          (const __attribute__((address_space(1))) void*)(Bg + (n0 + row) * ldb + k0 + scol),
          (__attribute__((address_space(3))) void*)(Bs + (c * 32 + wid * 8) * 64),
          16, 0, 0);
    }
    __syncthreads();
#pragma unroll
    for (int kk = 0; kk < 2; ++kk) {
      int kofs = kk * 32 + (lane >> 4) * 8;
      bf16x8 af[2], bfr[4];
#pragma unroll
      for (int i = 0; i < 2; ++i)
        af[i]  = *(const bf16x8*)&As[(wm * 32 + i * 16 + (lane & 15)) * 64 + kofs];
#pragma unroll
      for (int j = 0; j < 4; ++j)
        bfr[j] = *(const bf16x8*)&Bs[(wn * 64 + j * 16 + (lane & 15)) * 64 + kofs];
#pragma unroll
      for (int i = 0; i < 2; ++i)
#pragma unroll
        for (int j = 0; j < 4; ++j)
          acc[i][j] = __builtin_amdgcn_mfma_f32_16x16x32_bf16(af[i], bfr[j], acc[i][j], 0, 0, 0);
    }
    __syncthreads();
  }

  int lq = lane >> 4;
  int lr = lane & 15;

  if (MODE == 0 || MODE == 1) {
    float* ep = (float*)(smem_c + wid * 4608);   // wave-private, no barrier needed
    long cb  = (long)b * sC;
    int row0 = (int)m0 + wm * 32;
    int colb = (int)n0 + wn * 64;
#pragma unroll
    for (int i = 0; i < 2; ++i) {
#pragma unroll
      for (int j = 0; j < 4; ++j)
#pragma unroll
        for (int r = 0; r < 4; ++r)
          ep[(lq * 4 + r) * 72 + lr + j * 16] = acc[i][j][r];
#pragma unroll
      for (int p = 0; p < 4; ++p) {
        int rl = p * 4 + lq;
        f32x4 v = *(f32x4*)&ep[rl * 72 + lr * 4];
        long off = (long)(row0 + i * 16 + rl) * ldc + colb + lr * 4;
        if (MODE == 0) {
          u16v4 o;
#pragma unroll
          for (int t = 0; t < 4; ++t) o[t] = f2bf(v[t]);
          *(u16v4*)((u16*)Cout + cb + off) = o;
        } else {
          const float* R = Res + (long)b * sRes;
          f32v4 rv = *(const f32v4*)&R[off];
          f32v4 ov;
#pragma unroll
          for (int t = 0; t < 4; ++t) ov[t] = v[t] + rv[t];
          *(f32v4*)((float*)Cout + cb + off) = ov;
        }
      }
    }
  } else {
    // MODE 3: transposed bf16 store via LDS [128][72]
    u16* tT = (u16*)smem_c;
#pragma unroll
    for (int i = 0; i < 2; ++i)
#pragma unroll
      for (int j = 0; j < 4; ++j)
#pragma unroll
        for (int r = 0; r < 4; ++r)
          tT[(wn * 64 + j * 16 + lr) * 72 + wm * 32 + i * 16 + lq * 4 + r] = f2bf(acc[i][j][r]);
    __syncthreads();
    long cb = (long)b * sC;
    int ct  = tid >> 1;
    int seg = (tid & 1) * 32;
    u16* dst = (u16*)Cout + cb + (long)(n0 + ct) * ldc + m0 + seg;
    const u16* srcl = &tT[ct * 72 + seg];
#pragma unroll
    for (int q = 0; q < 4; ++q)
      *(u16v8*)(dst + q * 8) = *(const u16v8*)(srcl + q * 8);
  }
}

// ------- logits GEMM with FUSED channel softmax: attn = softmax(h_bf @ Wa^T) -------
// BM=64, BN=512 (full row), K=512. 256 threads = 4 waves; wave w owns cols [w*128, w*128+128).
// acc 4x8 frags. Softmax on f32 accumulators: in-lane over j, 16-lane shuffle, cross-wave LDS.
__global__ __launch_bounds__(256, 2) void gemm_sm(
    const u16* __restrict__ A,    // [32768 x 512] bf16
    const u16* __restrict__ Bw,   // [512 x 512] bf16 (w_attn)
    u16* __restrict__ C) {        // [32768 x 512] bf16 attn
  __shared__ __align__(16) char smem[73728];
  u16* As = (u16*)smem;                 // [64][64]
  u16* Bs = (u16*)(smem + 8192);        // [512][64]

  int nwg = gridDim.x;
  int flat = blockIdx.x;
  if ((nwg & 7) == 0) { int q = nwg >> 3; flat = (flat & 7) * q + (flat >> 3); }
  long m0 = (long)flat * 64;

  int tid = threadIdx.x;
  int lane = tid & 63;
  int wid = tid >> 6;

  int srow = wid * 8 + (lane >> 3);   // 0..31
  int scol = (lane & 7) * 8;

  f32x4 acc[4][8] = {};

  for (int k0 = 0; k0 < 512; k0 += 64) {
#pragma unroll
    for (int c = 0; c < 2; ++c) {
      int row = c * 32 + srow;
      __builtin_amdgcn_global_load_lds(
          (const __attribute__((address_space(1))) void*)(A + (m0 + row) * 512 + k0 + scol),
          (__attribute__((address_space(3))) void*)(As + (c * 32 + wid * 8) * 64),
          16, 0, 0);
    }
#pragma unroll
    for (int c = 0; c < 16; ++c) {
      int row = c * 32 + srow;
      __builtin_amdgcn_global_load_lds(
          (const __attribute__((address_space(1))) void*)(Bw + (long)row * 512 + k0 + scol),
          (__attribute__((address_space(3))) void*)(Bs + (c * 32 + wid * 8) * 64),
          16, 0, 0);
    }
    __syncthreads();
#pragma unroll
    for (int kk = 0; kk < 2; ++kk) {
      int kofs = kk * 32 + (lane >> 4) * 8;
      bf16x8 af[4], bfr[8];
#pragma unroll
      for (int i = 0; i < 4; ++i)
        af[i] = *(const bf16x8*)&As[(i * 16 + (lane & 15)) * 64 + kofs];
#pragma unroll
      for (int j = 0; j < 8; ++j)
        bfr[j] = *(const bf16x8*)&Bs[(wid * 128 + j * 16 + (lane & 15)) * 64 + kofs];
#pragma unroll
      for (int i = 0; i < 4; ++i)
#pragma unroll
        for (int j = 0; j < 8; ++j)
          acc[i][j] = __builtin_amdgcn_mfma_f32_16x16x32_bf16(af[i], bfr[j], acc[i][j], 0, 0, 0);
    }
    __syncthreads();
  }

  int lq = lane >> 4, lr = lane & 15;
  float* sm = (float*)smem;            // [64][4]
  float* ss = (float*)(smem + 1024);   // [64][4]

  // 1) row max: in-lane over 8 j-frags, 16-lane shuffle, cross-wave via LDS
#pragma unroll
  for (int i = 0; i < 4; ++i)
#pragma unroll
    for (int r = 0; r < 4; ++r) {
      float m = acc[i][0][r];
#pragma unroll
      for (int j = 1; j < 8; ++j) m = fmaxf(m, acc[i][j][r]);
#pragma unroll
      for (int o = 1; o < 16; o <<= 1) m = fmaxf(m, __shfl_xor(m, o, 16));
      if (lr == 0) sm[(i * 16 + lq * 4 + r) * 4 + wid] = m;
    }
  __syncthreads();
  // 2) exp + row sum
  float rinv[4][4];
#pragma unroll
  for (int i = 0; i < 4; ++i)
#pragma unroll
    for (int r = 0; r < 4; ++r) {
      f32v4 g4 = *(const f32v4*)&sm[(i * 16 + lq * 4 + r) * 4];
      float gm = fmaxf(fmaxf(g4[0], g4[1]), fmaxf(g4[2], g4[3]));
      float s = 0.f;
#pragma unroll
      for (int j = 0; j < 8; ++j) {
        float e = __expf(acc[i][j][r] - gm);
        acc[i][j][r] = e;
        s += e;
      }
#pragma unroll
      for (int o = 1; o < 16; o <<= 1) s += __shfl_xor(s, o, 16);
      if (lr == 0) ss[(i * 16 + lq * 4 + r) * 4 + wid] = s;
    }
  __syncthreads();
#pragma unroll
  for (int i = 0; i < 4; ++i)
#pragma unroll
    for (int r = 0; r < 4; ++r) {
      f32v4 g4 = *(const f32v4*)&ss[(i * 16 + lq * 4 + r) * 4];
      rinv[i][r] = 1.0f / (g4[0] + g4[1] + g4[2] + g4[3]);
    }
  __syncthreads();   // all sm/ss reads done before staging overwrites

  // 3) scale + coalesced bf16 store via wave-private LDS staging (two 64-col halves)
  float* ep = (float*)(smem + wid * 4608);
#pragma unroll
  for (int i = 0; i < 4; ++i) {
#pragma unroll
    for (int jh = 0; jh < 2; ++jh) {
#pragma unroll
      for (int j = 0; j < 4; ++j)
#pragma unroll
        for (int r = 0; r < 4; ++r)
          ep[(lq * 4 + r) * 72 + lr + j * 16] = acc[i][jh * 4 + j][r] * rinv[i][r];
#pragma unroll
      for (int p = 0; p < 4; ++p) {
        int rl = p * 4 + lq;
        f32x4 v = *(f32x4*)&ep[rl * 72 + lr * 4];
        u16v4 o;
#pragma unroll
        for (int t = 0; t < 4; ++t) o[t] = f2bf(v[t]);
        *(u16v4*)&C[(m0 + i * 16 + rl) * 512 + wid * 128 + jh * 64 + lr * 4] = o;
      }
    }
  }
}

// ---------------- host ----------------
extern "C" void kernel_launch(void* const* d_in, const int* in_sizes, int n_in,
                              void* d_out, int out_size, void* d_ws, size_t ws_size,
                              hipStream_t stream) {
  (void)in_sizes; (void)n_in; (void)out_size; (void)ws_size;
  const float* h    = (const float*)d_in[0];
  const float* hret = (const float*)d_in[1];
  const float* Wc   = (const float*)d_in[2];
  const float* Wa   = (const float*)d_in[3];
  const float* Wk   = (const float*)d_in[4];
  const float* Wv   = (const float*)d_in[5];
  const float* Wo   = (const float*)d_in[6];
  float* out = (float*)d_out;
  char*  ws  = (char*)d_ws;

  constexpr long MB = 1024 * 1024;
  // workspace (peak 132 MB):
  //  0.. 4MB : weights bf16 (+ w_vT)
  //  4..36MB : h_bf (live: cvt_dual .. gemm_sm) / gparts (live: Gram .. reduce8)
  // 36..68MB : attn (live: gemm_sm .. final)
  // 68..84MB : g_bf(4) u_mat(1) v1(4) f2t(4)
  // 84..132MB: xt (live: cvt_dual/hr .. Gram)
  u16*   w_cond = (u16*)(ws + 0);
  u16*   w_attn = (u16*)(ws + 786432);
  u16*   w_k    = (u16*)(ws + 1310720);
  u16*   w_v    = (u16*)(ws + 1835008);
  u16*   w_out  = (u16*)(ws + 2359296);
  u16*   w_vT   = (u16*)(ws + 2883584);
  u16*   h_bf   = (u16*)(ws + 4 * MB);
  u16*   gparts = (u16*)(ws + 4 * MB);    // overlay h_bf (dead after gemm_sm)
  u16*   attn   = (u16*)(ws + 36 * MB);
  u16*   g_bf   = (u16*)(ws + 68 * MB);
  u16*   u_mat  = (u16*)(ws + 72 * MB);
  u16*   v1     = (u16*)(ws + 73 * MB);
  u16*   f2t    = (u16*)(ws + 77 * MB);
  u16*   xt     = (u16*)(ws + 84 * MB);

  // 1) h: fused convert + transpose  (h_bf rows + xt[:, 0:4096])
  cvt_dual<<<dim3(64, 8, 8), 256, 0, stream>>>(h, h_bf, xt, 2097152L, 3145728L);
  // 2) all weights in one dispatch
  prep_weights<<<640, 256, 0, stream>>>(Wc, Wa, Wk, Wv, Wo,
      w_cond, w_attn, w_k, w_v, w_vT, w_out);

  // 3) hr = hret(f32) @ W_cond^T, reg-staged convert, written TRANSPOSED into xt[:, 4096:6144]
  gemm64<3, true><<<dim3(4, 32, 8), 256, 0, stream>>>(hret, w_cond, xt + 4096, nullptr,
      768, 768, 768, 6144, 1572864L, 0, 3145728L, 0);

  // 4) attn = softmax(h_bf @ W_attn^T) fused, all batches flat (M=32768)
  gemm_sm<<<512, 256, 0, stream>>>(h_bf, w_attn, attn);

  // 5) Gram G = X^T X via NT(xt, xt), split-K=8 bf16 partials, reduce -> bf16
  gemm_nt<0><<<dim3(4, 4, 64), 256, 0, stream>>>(xt, xt, gparts, nullptr,
      768, 6144, 6144, 512, 3145728L, 3145728L, 2097152L, 262144L, 0, 8);
  reduce8_bf16<<<1024, 256, 0, stream>>>(gparts, g_bf);

  // 6) f2^T = W_out W_v G W_k^T (G symmetric):
  gemm64<0, false><<<dim3(4, 8, 1), 256, 0, stream>>>(w_out, w_vT, u_mat, nullptr,
      512, 512, 512, 512, 0, 0, 0, 0);
  gemm64<0, false><<<dim3(4, 8, 8), 256, 0, stream>>>(u_mat, g_bf, v1, nullptr,
      512, 512, 512, 512, 0, 262144L, 262144L, 0);
  gemm64<0, false><<<dim3(4, 8, 8), 256, 0, stream>>>(v1, w_k, f2t, nullptr,
      512, 512, 512, 512, 262144L, 0, 262144L, 0);

  // 7) out = h + attn @ f2  (fused residual, f32 out)
  gemm64<1, false><<<dim3(4, 64, 8), 256, 0, stream>>>(attn, f2t, out, h,
      512, 512, 512, 512, 2097152L, 262144L, 2097152L, 2097152L);
}

// Round 6
// 217.391 us; speedup vs baseline: 1.2581x; 1.0417x over previous
//
#include <hip/hip_runtime.h>
#include <hip/hip_bf16.h>

// Problem: B=8, N=4096, M=2048, IN=512, D=512, CTX=768
// out = h + attn @ f2,  attn = softmax(h W_a^T),  f2^T = W_out W_v G W_k^T,
// G = X^T X (symmetric), X = [h; h_retrieved W_c^T]  (all bf16 MFMA internally)

typedef unsigned short u16;
typedef __bf16 bf16x8 __attribute__((ext_vector_type(8)));
typedef float  f32x4  __attribute__((ext_vector_type(4)));
typedef float  f32v4  __attribute__((ext_vector_type(4)));
typedef u16    u16v4  __attribute__((ext_vector_type(4)));
typedef u16    u16v8  __attribute__((ext_vector_type(8)));

__device__ __forceinline__ u16 f2bf(float f) {
  unsigned u = __builtin_bit_cast(unsigned, f);
  u = u + 0x7FFFu + ((u >> 16) & 1u);   // RNE; inputs are finite
  return (u16)(u >> 16);
}
__device__ __forceinline__ float bf2f(u16 s) {
  return __builtin_bit_cast(float, (unsigned)s << 16);
}

// ------- fused f32->bf16 convert + dual write (normal layout + transposed) -------
__global__ __launch_bounds__(256) void cvt_dual(const float* __restrict__ src,
                                                u16* __restrict__ dstN,
                                                u16* __restrict__ dstT,
                                                long src_bs, long dstT_bs) {
  __shared__ u16 tile[64][72];
  long bz = blockIdx.z;
  const float* S = src + bz * src_bs;
  u16* DN = dstN + bz * src_bs;
  u16* DT = dstT + bz * dstT_bs;
  int r0 = blockIdx.x * 64;
  int c0 = blockIdx.y * 64;
  int t  = threadIdx.x;
  int tr = t >> 2;
  int tc = (t & 3) * 16;
  const float* sp = &S[(long)(r0 + tr) * 512 + c0 + tc];
#pragma unroll
  for (int q = 0; q < 2; ++q) {
    f32v4 a = *(const f32v4*)(sp + q * 8);
    f32v4 b = *(const f32v4*)(sp + q * 8 + 4);
    u16v8 o;
    o[0] = f2bf(a[0]); o[1] = f2bf(a[1]); o[2] = f2bf(a[2]); o[3] = f2bf(a[3]);
    o[4] = f2bf(b[0]); o[5] = f2bf(b[1]); o[6] = f2bf(b[2]); o[7] = f2bf(b[3]);
    *(u16v8*)&DN[(long)(r0 + tr) * 512 + c0 + tc + q * 8] = o;
    *(u16v8*)&tile[tr][tc + q * 8] = o;
  }
  __syncthreads();
  int tr2 = t >> 3;
  int tc2 = (t & 7) * 8;
#pragma unroll
  for (int it = 0; it < 2; ++it) {
    int cr = it * 32 + tr2;
    u16v8 o;
#pragma unroll
    for (int j = 0; j < 8; ++j) o[j] = tile[tc2 + j][cr];
    *(u16v8*)&DT[(long)(c0 + cr) * 6144 + r0 + tc2] = o;
  }
}

// ------- all weight prep in ONE dispatch -------
__global__ __launch_bounds__(256) void prep_weights(
    const float* __restrict__ Wc, const float* __restrict__ Wa,
    const float* __restrict__ Wk, const float* __restrict__ Wv,
    const float* __restrict__ Wo,
    u16* __restrict__ wc, u16* __restrict__ wa, u16* __restrict__ wk,
    u16* __restrict__ wv, u16* __restrict__ wvT, u16* __restrict__ wo) {
  __shared__ u16 tile[64][72];
  int bx = blockIdx.x;
  int t = threadIdx.x;
  if (bx < 576) {
    const float* src; u16* dst; long base;
    if (bx < 192)      { src = Wc; dst = wc; base = (long)bx * 2048; }
    else if (bx < 320) { src = Wa; dst = wa; base = (long)(bx - 192) * 2048; }
    else if (bx < 448) { src = Wk; dst = wk; base = (long)(bx - 320) * 2048; }
    else               { src = Wo; dst = wo; base = (long)(bx - 448) * 2048; }
    long i = base + (long)t * 8;
    f32v4 a = *(const f32v4*)(src + i);
    f32v4 b = *(const f32v4*)(src + i + 4);
    u16v8 o;
    o[0] = f2bf(a[0]); o[1] = f2bf(a[1]); o[2] = f2bf(a[2]); o[3] = f2bf(a[3]);
    o[4] = f2bf(b[0]); o[5] = f2bf(b[1]); o[6] = f2bf(b[2]); o[7] = f2bf(b[3]);
    *(u16v8*)(dst + i) = o;
  } else {
    int b2 = bx - 576;
    int r0 = (b2 >> 3) * 64, c0 = (b2 & 7) * 64;
    int tr = t >> 2, tc = (t & 3) * 16;
    const float* sp = &Wv[(long)(r0 + tr) * 512 + c0 + tc];
#pragma unroll
    for (int q = 0; q < 2; ++q) {
      f32v4 a = *(const f32v4*)(sp + q * 8);
      f32v4 b = *(const f32v4*)(sp + q * 8 + 4);
      u16v8 o;
      o[0] = f2bf(a[0]); o[1] = f2bf(a[1]); o[2] = f2bf(a[2]); o[3] = f2bf(a[3]);
      o[4] = f2bf(b[0]); o[5] = f2bf(b[1]); o[6] = f2bf(b[2]); o[7] = f2bf(b[3]);
      *(u16v8*)&wv[(long)(r0 + tr) * 512 + c0 + tc + q * 8] = o;
      *(u16v8*)&tile[tr][tc + q * 8] = o;
    }
    __syncthreads();
    int tr2 = t >> 3, tc2 = (t & 7) * 8;
#pragma unroll
    for (int it = 0; it < 2; ++it) {
      int cr = it * 32 + tr2;
      u16v8 o;
#pragma unroll
      for (int j = 0; j < 8; ++j) o[j] = tile[tc2 + j][cr];
      *(u16v8*)&wvT[(long)(c0 + cr) * 512 + r0 + tc2] = o;
    }
  }
}

// -------- reduce 8 split-K bf16 slices -> bf16 (per batch 512x512) --------
__global__ __launch_bounds__(256) void reduce8_bf16(const u16* __restrict__ parts,
                                                    u16* __restrict__ out) {
  long i = (((long)blockIdx.x * 256) + threadIdx.x) * 8;
  long b = i >> 18;
  long r = i & 262143;
  const u16* p = parts + b * 2097152 + r;
  float acc[8] = {};
#pragma unroll
  for (int s = 0; s < 8; ++s) {
    u16v8 v = *(const u16v8*)(p + (long)s * 262144);
#pragma unroll
    for (int j = 0; j < 8; ++j) acc[j] += bf2f(v[j]);
  }
  u16v8 o;
#pragma unroll
  for (int j = 0; j < 8; ++j) o[j] = f2bf(acc[j]);
  *(u16v8*)(out + i) = o;
}

// ------------- NT GEMM 128x128, double-buffered LDS (T3-minimum 2-phase) -------------
// Used for Gram. LDS 64KB -> 2 blocks/CU (grid is exactly 2/CU).
// LDS layout: As0 @0, As1 @16384, Bs0 @32768, Bs1 @49152
template <int MODE>
__global__ __launch_bounds__(256) void gemm_nt(
    const u16* __restrict__ A, const u16* __restrict__ B, void* __restrict__ Cout,
    const float* __restrict__ Res, int K, int lda, int ldb, int ldc,
    long sA, long sB, long sC, long sS, long sRes, int kslices) {
  __shared__ __align__(16) char smem_c[65536];

  int gx = gridDim.x, gy = gridDim.y;
  int nwg = gx * gy * (int)gridDim.z;
  int flat = blockIdx.x + gx * (blockIdx.y + gy * blockIdx.z);
  if ((nwg & 7) == 0) { int q = nwg >> 3; flat = (flat & 7) * q + (flat >> 3); }
  int bx = flat % gx; int tmp = flat / gx; int by = tmp % gy; int z = tmp / gy;

  int b = z / kslices;
  int s = z - b * kslices;
  const u16* Ag = A + (long)b * sA + (long)s * K;
  const u16* Bg = B + (long)b * sB + (long)s * K;

  long m0 = (long)bx * 128;
  long n0 = (long)by * 128;

  int tid  = threadIdx.x;
  int lane = tid & 63;
  int wid  = tid >> 6;
  int wm = wid >> 1, wn = wid & 1;

  int srow = wid * 8 + (lane >> 3);
  int scol = (lane & 7) * 8;

  auto stageA = [&](u16* Asd, int k0) {
#pragma unroll
    for (int c = 0; c < 4; ++c) {
      int row = c * 32 + srow;
      __builtin_amdgcn_global_load_lds(
          (const __attribute__((address_space(1))) void*)(Ag + (m0 + row) * lda + k0 + scol),
          (__attribute__((address_space(3))) void*)(Asd + (c * 32 + wid * 8) * 64),
          16, 0, 0);
    }
  };
  auto stageB = [&](u16* Bsd, int k0) {
#pragma unroll
    for (int c = 0; c < 4; ++c) {
      int row = c * 32 + srow;
      __builtin_amdgcn_global_load_lds(
          (const __attribute__((address_space(1))) void*)(Bg + (n0 + row) * ldb + k0 + scol),
          (__attribute__((address_space(3))) void*)(Bsd + (c * 32 + wid * 8) * 64),
          16, 0, 0);
    }
  };

  f32x4 acc[4][4] = {};
  int nk = K >> 6;

  stageA((u16*)smem_c, 0);
  stageB((u16*)(smem_c + 32768), 0);
  __syncthreads();

  for (int t = 0; t < nk; ++t) {
    u16* Asc = (u16*)(smem_c + (t & 1) * 16384);
    u16* Bsc = (u16*)(smem_c + 32768 + (t & 1) * 16384);
    if (t + 1 < nk) {
      u16* Asn = (u16*)(smem_c + ((t + 1) & 1) * 16384);
      u16* Bsn = (u16*)(smem_c + 32768 + ((t + 1) & 1) * 16384);
      stageA(Asn, (t + 1) * 64);
      stageB(Bsn, (t + 1) * 64);
    }
#pragma unroll
    for (int kk = 0; kk < 2; ++kk) {
      int kofs = kk * 32 + (lane >> 4) * 8;
      bf16x8 af[4], bfr[4];
#pragma unroll
      for (int i = 0; i < 4; ++i) {
        af[i]  = *(const bf16x8*)&Asc[(wm * 64 + i * 16 + (lane & 15)) * 64 + kofs];
        bfr[i] = *(const bf16x8*)&Bsc[(wn * 64 + i * 16 + (lane & 15)) * 64 + kofs];
      }
#pragma unroll
      for (int i = 0; i < 4; ++i)
#pragma unroll
        for (int j = 0; j < 4; ++j)
          acc[i][j] = __builtin_amdgcn_mfma_f32_16x16x32_bf16(af[i], bfr[j], acc[i][j], 0, 0, 0);
    }
    __syncthreads();
  }

  float* ep = (float*)(smem_c + wid * 4608);
  long cb  = (long)b * sC + (long)s * sS;
  int row0 = (int)m0 + wm * 64;
  int colb = (int)n0 + wn * 64;
  int lq = lane >> 4;
  int lr = lane & 15;

#pragma unroll
  for (int i = 0; i < 4; ++i) {
#pragma unroll
    for (int j = 0; j < 4; ++j)
#pragma unroll
      for (int r = 0; r < 4; ++r)
        ep[(lq * 4 + r) * 72 + lr + j * 16] = acc[i][j][r];
#pragma unroll
    for (int p = 0; p < 4; ++p) {
      int rl = p * 4 + lq;
      f32x4 v = *(f32x4*)&ep[rl * 72 + lr * 4];
      long off = (long)(row0 + i * 16 + rl) * ldc + colb + lr * 4;
      if (MODE == 0) {
        u16v4 o;
#pragma unroll
        for (int t2 = 0; t2 < 4; ++t2) o[t2] = f2bf(v[t2]);
        *(u16v4*)((u16*)Cout + cb + off) = o;
      } else {
        const float* R = Res + (long)b * sRes;
        f32v4 rv = *(const f32v4*)&R[off];
        f32v4 ov;
#pragma unroll
        for (int t2 = 0; t2 < 4; ++t2) ov[t2] = v[t2] + rv[t2];
        *(f32v4*)((float*)Cout + cb + off) = ov;
      }
    }
  }
}

// ------------- NT GEMM 64x128, double-buffered (T3-minimum 2-phase) -------------
// LDS 48KB -> 3 blocks/CU. MODE: 0=bf16, 1=f32+residual, 3=bf16 transposed store.
// AF32: A is f32 in global; loads issued at loop top, convert+ds_write AFTER MFMAs (T14).
// LDS layout: As0 @0 (8KB), As1 @8192, Bs0 @16384 (16KB), Bs1 @32768
template <int MODE, bool AF32>
__global__ __launch_bounds__(256) void gemm64(
    const void* __restrict__ Ap, const u16* __restrict__ B, void* __restrict__ Cout,
    const float* __restrict__ Res, int K, int lda, int ldb, int ldc,
    long sA, long sB, long sC, long sRes) {
  __shared__ __align__(16) char smem_c[49152];

  int gx = gridDim.x, gy = gridDim.y;
  int nwg = gx * gy * (int)gridDim.z;
  int flat = blockIdx.x + gx * (blockIdx.y + gy * blockIdx.z);
  if ((nwg & 7) == 0) { int q = nwg >> 3; flat = (flat & 7) * q + (flat >> 3); }
  int bx = flat % gx; int tmp = flat / gx; int by = tmp % gy; int b = tmp / gy;

  long n0 = (long)bx * 128;
  long m0 = (long)by * 64;
  const u16* Ag = (const u16*)Ap + (long)b * sA;
  const float* Af = (const float*)Ap + (long)b * sA;
  const u16* Bg = B + (long)b * sB;

  int tid  = threadIdx.x;
  int lane = tid & 63;
  int wid  = tid >> 6;
  int wm = wid >> 1, wn = wid & 1;

  int srow = wid * 8 + (lane >> 3);
  int scol = (lane & 7) * 8;
  int arow = tid >> 2;            // AF32: 0..63
  int acol = (tid & 3) * 16;      // AF32: f32 col

  auto stageA = [&](u16* Asd, int k0) {
#pragma unroll
    for (int c = 0; c < 2; ++c) {
      int row = c * 32 + srow;
      __builtin_amdgcn_global_load_lds(
          (const __attribute__((address_space(1))) void*)(Ag + (m0 + row) * lda + k0 + scol),
          (__attribute__((address_space(3))) void*)(Asd + (c * 32 + wid * 8) * 64),
          16, 0, 0);
    }
  };
  auto stageB = [&](u16* Bsd, int k0) {
#pragma unroll
    for (int c = 0; c < 4; ++c) {
      int row = c * 32 + srow;
      __builtin_amdgcn_global_load_lds(
          (const __attribute__((address_space(1))) void*)(Bg + (n0 + row) * ldb + k0 + scol),
          (__attribute__((address_space(3))) void*)(Bsd + (c * 32 + wid * 8) * 64),
          16, 0, 0);
    }
  };
  auto cvtA = [&](u16* Asd, const f32v4& x0, const f32v4& x1,
                  const f32v4& x2, const f32v4& x3) {
    u16v8 o0, o1;
    o0[0] = f2bf(x0[0]); o0[1] = f2bf(x0[1]); o0[2] = f2bf(x0[2]); o0[3] = f2bf(x0[3]);
    o0[4] = f2bf(x1[0]); o0[5] = f2bf(x1[1]); o0[6] = f2bf(x1[2]); o0[7] = f2bf(x1[3]);
    o1[0] = f2bf(x2[0]); o1[1] = f2bf(x2[1]); o1[2] = f2bf(x2[2]); o1[3] = f2bf(x2[3]);
    o1[4] = f2bf(x3[0]); o1[5] = f2bf(x3[1]); o1[6] = f2bf(x3[2]); o1[7] = f2bf(x3[3]);
    *(u16v8*)&Asd[arow * 64 + acol] = o0;
    *(u16v8*)&Asd[arow * 64 + acol + 8] = o1;
  };

  f32x4 acc[2][4] = {};
  int nk = K >> 6;

  // prologue: stage tile 0 into buffer 0
  if constexpr (AF32) {
    const float* sp = Af + (m0 + arow) * (long)lda + acol;
    f32v4 x0 = *(const f32v4*)sp;
    f32v4 x1 = *(const f32v4*)(sp + 4);
    f32v4 x2 = *(const f32v4*)(sp + 8);
    f32v4 x3 = *(const f32v4*)(sp + 12);
    cvtA((u16*)smem_c, x0, x1, x2, x3);
  } else {
    stageA((u16*)smem_c, 0);
  }
  stageB((u16*)(smem_c + 16384), 0);
  __syncthreads();

  for (int t = 0; t < nk; ++t) {
    u16* Asc = (u16*)(smem_c + (t & 1) * 8192);
    u16* Bsc = (u16*)(smem_c + 16384 + (t & 1) * 16384);
    u16* Asn = (u16*)(smem_c + ((t + 1) & 1) * 8192);
    u16* Bsn = (u16*)(smem_c + 16384 + ((t + 1) & 1) * 16384);
    bool more = (t + 1) < nk;
    f32v4 x0, x1, x2, x3;
    if (more) {
      if constexpr (AF32) {
        const float* sp = Af + (m0 + arow) * (long)lda + (t + 1) * 64 + acol;
        x0 = *(const f32v4*)sp;
        x1 = *(const f32v4*)(sp + 4);
        x2 = *(const f32v4*)(sp + 8);
        x3 = *(const f32v4*)(sp + 12);
      } else {
        stageA(Asn, (t + 1) * 64);
      }
      stageB(Bsn, (t + 1) * 64);
    }
#pragma unroll
    for (int kk = 0; kk < 2; ++kk) {
      int kofs = kk * 32 + (lane >> 4) * 8;
      bf16x8 af[2], bfr[4];
#pragma unroll
      for (int i = 0; i < 2; ++i)
        af[i]  = *(const bf16x8*)&Asc[(wm * 32 + i * 16 + (lane & 15)) * 64 + kofs];
#pragma unroll
      for (int j = 0; j < 4; ++j)
        bfr[j] = *(const bf16x8*)&Bsc[(wn * 64 + j * 16 + (lane & 15)) * 64 + kofs];
#pragma unroll
      for (int i = 0; i < 2; ++i)
#pragma unroll
        for (int j = 0; j < 4; ++j)
          acc[i][j] = __builtin_amdgcn_mfma_f32_16x16x32_bf16(af[i], bfr[j], acc[i][j], 0, 0, 0);
    }
    if constexpr (AF32) {
      if (more) cvtA(Asn, x0, x1, x2, x3);
    }
    __syncthreads();
  }

  int lq = lane >> 4;
  int lr = lane & 15;

  if (MODE == 0 || MODE == 1) {
    float* ep = (float*)(smem_c + wid * 4608);   // wave-private scratch
    long cb  = (long)b * sC;
    int row0 = (int)m0 + wm * 32;
    int colb = (int)n0 + wn * 64;
#pragma unroll
    for (int i = 0; i < 2; ++i) {
#pragma unroll
      for (int j = 0; j < 4; ++j)
#pragma unroll
        for (int r = 0; r < 4; ++r)
          ep[(lq * 4 + r) * 72 + lr + j * 16] = acc[i][j][r];
#pragma unroll
      for (int p = 0; p < 4; ++p) {
        int rl = p * 4 + lq;
        f32x4 v = *(f32x4*)&ep[rl * 72 + lr * 4];
        long off = (long)(row0 + i * 16 + rl) * ldc + colb + lr * 4;
        if (MODE == 0) {
          u16v4 o;
#pragma unroll
          for (int t2 = 0; t2 < 4; ++t2) o[t2] = f2bf(v[t2]);
          *(u16v4*)((u16*)Cout + cb + off) = o;
        } else {
          const float* R = Res + (long)b * sRes;
          f32v4 rv = *(const f32v4*)&R[off];
          f32v4 ov;
#pragma unroll
          for (int t2 = 0; t2 < 4; ++t2) ov[t2] = v[t2] + rv[t2];
          *(f32v4*)((float*)Cout + cb + off) = ov;
        }
      }
    }
  } else {
    // MODE 3: transposed bf16 store via LDS [128][72] (after final barrier: safe)
    u16* tT = (u16*)smem_c;
#pragma unroll
    for (int i = 0; i < 2; ++i)
#pragma unroll
      for (int j = 0; j < 4; ++j)
#pragma unroll
        for (int r = 0; r < 4; ++r)
          tT[(wn * 64 + j * 16 + lr) * 72 + wm * 32 + i * 16 + lq * 4 + r] = f2bf(acc[i][j][r]);
    __syncthreads();
    long cb = (long)b * sC;
    int ct  = tid >> 1;
    int seg = (tid & 1) * 32;
    u16* dst = (u16*)Cout + cb + (long)(n0 + ct) * ldc + m0 + seg;
    const u16* srcl = &tT[ct * 72 + seg];
#pragma unroll
    for (int q = 0; q < 4; ++q)
      *(u16v8*)(dst + q * 8) = *(const u16v8*)(srcl + q * 8);
  }
}

// ------- logits GEMM with FUSED channel softmax: attn = softmax(h_bf @ Wa^T) -------
__global__ __launch_bounds__(256, 2) void gemm_sm(
    const u16* __restrict__ A,    // [32768 x 512] bf16
    const u16* __restrict__ Bw,   // [512 x 512] bf16 (w_attn)
    u16* __restrict__ C) {        // [32768 x 512] bf16 attn
  __shared__ __align__(16) char smem[73728];
  u16* As = (u16*)smem;                 // [64][64]
  u16* Bs = (u16*)(smem + 8192);        // [512][64]

  int nwg = gridDim.x;
  int flat = blockIdx.x;
  if ((nwg & 7) == 0) { int q = nwg >> 3; flat = (flat & 7) * q + (flat >> 3); }
  long m0 = (long)flat * 64;

  int tid = threadIdx.x;
  int lane = tid & 63;
  int wid = tid >> 6;

  int srow = wid * 8 + (lane >> 3);
  int scol = (lane & 7) * 8;

  f32x4 acc[4][8] = {};

  for (int k0 = 0; k0 < 512; k0 += 64) {
#pragma unroll
    for (int c = 0; c < 2; ++c) {
      int row = c * 32 + srow;
      __builtin_amdgcn_global_load_lds(
          (const __attribute__((address_space(1))) void*)(A + (m0 + row) * 512 + k0 + scol),
          (__attribute__((address_space(3))) void*)(As + (c * 32 + wid * 8) * 64),
          16, 0, 0);
    }
#pragma unroll
    for (int c = 0; c < 16; ++c) {
      int row = c * 32 + srow;
      __builtin_amdgcn_global_load_lds(
          (const __attribute__((address_space(1))) void*)(Bw + (long)row * 512 + k0 + scol),
          (__attribute__((address_space(3))) void*)(Bs + (c * 32 + wid * 8) * 64),
          16, 0, 0);
    }
    __syncthreads();
#pragma unroll
    for (int kk = 0; kk < 2; ++kk) {
      int kofs = kk * 32 + (lane >> 4) * 8;
      bf16x8 af[4], bfr[8];
#pragma unroll
      for (int i = 0; i < 4; ++i)
        af[i] = *(const bf16x8*)&As[(i * 16 + (lane & 15)) * 64 + kofs];
#pragma unroll
      for (int j = 0; j < 8; ++j)
        bfr[j] = *(const bf16x8*)&Bs[(wid * 128 + j * 16 + (lane & 15)) * 64 + kofs];
#pragma unroll
      for (int i = 0; i < 4; ++i)
#pragma unroll
        for (int j = 0; j < 8; ++j)
          acc[i][j] = __builtin_amdgcn_mfma_f32_16x16x32_bf16(af[i], bfr[j], acc[i][j], 0, 0, 0);
    }
    __syncthreads();
  }

  int lq = lane >> 4, lr = lane & 15;
  float* sm = (float*)smem;            // [64][4]
  float* ss = (float*)(smem + 1024);   // [64][4]

#pragma unroll
  for (int i = 0; i < 4; ++i)
#pragma unroll
    for (int r = 0; r < 4; ++r) {
      float m = acc[i][0][r];
#pragma unroll
      for (int j = 1; j < 8; ++j) m = fmaxf(m, acc[i][j][r]);
#pragma unroll
      for (int o = 1; o < 16; o <<= 1) m = fmaxf(m, __shfl_xor(m, o, 16));
      if (lr == 0) sm[(i * 16 + lq * 4 + r) * 4 + wid] = m;
    }
  __syncthreads();
  float rinv[4][4];
#pragma unroll
  for (int i = 0; i < 4; ++i)
#pragma unroll
    for (int r = 0; r < 4; ++r) {
      f32v4 g4 = *(const f32v4*)&sm[(i * 16 + lq * 4 + r) * 4];
      float gm = fmaxf(fmaxf(g4[0], g4[1]), fmaxf(g4[2], g4[3]));
      float s = 0.f;
#pragma unroll
      for (int j = 0; j < 8; ++j) {
        float e = __expf(acc[i][j][r] - gm);
        acc[i][j][r] = e;
        s += e;
      }
#pragma unroll
      for (int o = 1; o < 16; o <<= 1) s += __shfl_xor(s, o, 16);
      if (lr == 0) ss[(i * 16 + lq * 4 + r) * 4 + wid] = s;
    }
  __syncthreads();
#pragma unroll
  for (int i = 0; i < 4; ++i)
#pragma unroll
    for (int r = 0; r < 4; ++r) {
      f32v4 g4 = *(const f32v4*)&ss[(i * 16 + lq * 4 + r) * 4];
      rinv[i][r] = 1.0f / (g4[0] + g4[1] + g4[2] + g4[3]);
    }
  __syncthreads();

  float* ep = (float*)(smem + wid * 4608);
#pragma unroll
  for (int i = 0; i < 4; ++i) {
#pragma unroll
    for (int jh = 0; jh < 2; ++jh) {
#pragma unroll
      for (int j = 0; j < 4; ++j)
#pragma unroll
        for (int r = 0; r < 4; ++r)
          ep[(lq * 4 + r) * 72 + lr + j * 16] = acc[i][jh * 4 + j][r] * rinv[i][r];
#pragma unroll
      for (int p = 0; p < 4; ++p) {
        int rl = p * 4 + lq;
        f32x4 v = *(f32x4*)&ep[rl * 72 + lr * 4];
        u16v4 o;
#pragma unroll
        for (int t = 0; t < 4; ++t) o[t] = f2bf(v[t]);
        *(u16v4*)&C[(m0 + i * 16 + rl) * 512 + wid * 128 + jh * 64 + lr * 4] = o;
      }
    }
  }
}

// ---------------- host ----------------
extern "C" void kernel_launch(void* const* d_in, const int* in_sizes, int n_in,
                              void* d_out, int out_size, void* d_ws, size_t ws_size,
                              hipStream_t stream) {
  (void)in_sizes; (void)n_in; (void)out_size; (void)ws_size;
  const float* h    = (const float*)d_in[0];
  const float* hret = (const float*)d_in[1];
  const float* Wc   = (const float*)d_in[2];
  const float* Wa   = (const float*)d_in[3];
  const float* Wk   = (const float*)d_in[4];
  const float* Wv   = (const float*)d_in[5];
  const float* Wo   = (const float*)d_in[6];
  float* out = (float*)d_out;
  char*  ws  = (char*)d_ws;

  constexpr long MB = 1024 * 1024;
  u16*   w_cond = (u16*)(ws + 0);
  u16*   w_attn = (u16*)(ws + 786432);
  u16*   w_k    = (u16*)(ws + 1310720);
  u16*   w_v    = (u16*)(ws + 1835008);
  u16*   w_out  = (u16*)(ws + 2359296);
  u16*   w_vT   = (u16*)(ws + 2883584);
  u16*   h_bf   = (u16*)(ws + 4 * MB);
  u16*   gparts = (u16*)(ws + 4 * MB);    // overlay h_bf (dead after gemm_sm)
  u16*   attn   = (u16*)(ws + 36 * MB);
  u16*   g_bf   = (u16*)(ws + 68 * MB);
  u16*   u_mat  = (u16*)(ws + 72 * MB);
  u16*   v1     = (u16*)(ws + 73 * MB);
  u16*   f2t    = (u16*)(ws + 77 * MB);
  u16*   xt     = (u16*)(ws + 84 * MB);

  // 1) h: fused convert + transpose  (h_bf rows + xt[:, 0:4096])
  cvt_dual<<<dim3(64, 8, 8), 256, 0, stream>>>(h, h_bf, xt, 2097152L, 3145728L);
  // 2) all weights in one dispatch
  prep_weights<<<640, 256, 0, stream>>>(Wc, Wa, Wk, Wv, Wo,
      w_cond, w_attn, w_k, w_v, w_vT, w_out);

  // 3) hr = hret(f32) @ W_cond^T, reg-staged convert, written TRANSPOSED into xt[:, 4096:6144]
  gemm64<3, true><<<dim3(4, 32, 8), 256, 0, stream>>>(hret, w_cond, xt + 4096, nullptr,
      768, 768, 768, 6144, 1572864L, 0, 3145728L, 0);

  // 4) attn = softmax(h_bf @ W_attn^T) fused, all batches flat (M=32768)
  gemm_sm<<<512, 256, 0, stream>>>(h_bf, w_attn, attn);

  // 5) Gram G = X^T X via NT(xt, xt), split-K=8 bf16 partials, reduce -> bf16
  gemm_nt<0><<<dim3(4, 4, 64), 256, 0, stream>>>(xt, xt, gparts, nullptr,
      768, 6144, 6144, 512, 3145728L, 3145728L, 2097152L, 262144L, 0, 8);
  reduce8_bf16<<<1024, 256, 0, stream>>>(gparts, g_bf);

  // 6) f2^T = W_out W_v G W_k^T (G symmetric):
  gemm64<0, false><<<dim3(4, 8, 1), 256, 0, stream>>>(w_out, w_vT, u_mat, nullptr,
      512, 512, 512, 512, 0, 0, 0, 0);
  gemm64<0, false><<<dim3(4, 8, 8), 256, 0, stream>>>(u_mat, g_bf, v1, nullptr,
      512, 512, 512, 512, 0, 262144L, 262144L, 0);
  gemm64<0, false><<<dim3(4, 8, 8), 256, 0, stream>>>(v1, w_k, f2t, nullptr,
      512, 512, 512, 512, 262144L, 0, 262144L, 0);

  // 7) out = h + attn @ f2  (fused residual, f32 out)
  gemm64<1, false><<<dim3(4, 64, 8), 256, 0, stream>>>(attn, f2t, out, h,
      512, 512, 512, 512, 2097152L, 262144L, 2097152L, 2097152L);
}

// Round 7
// 213.903 us; speedup vs baseline: 1.2786x; 1.0163x over previous
//
#include <hip/hip_runtime.h>
#include <hip/hip_bf16.h>

// Problem: B=8, N=4096, M=2048, IN=512, D=512, CTX=768
// out = h + attn @ f2,  attn = softmax(h W_a^T),  f2^T = W_out W_v G W_k^T,
// G = X^T X (symmetric), X = [h; h_retrieved W_c^T]  (all bf16 MFMA internally)

typedef unsigned short u16;
typedef __bf16 bf16x8 __attribute__((ext_vector_type(8)));
typedef float  f32x4  __attribute__((ext_vector_type(4)));
typedef float  f32v4  __attribute__((ext_vector_type(4)));
typedef u16    u16v4  __attribute__((ext_vector_type(4)));
typedef u16    u16v8  __attribute__((ext_vector_type(8)));

__device__ __forceinline__ u16 f2bf(float f) {
  unsigned u = __builtin_bit_cast(unsigned, f);
  u = u + 0x7FFFu + ((u >> 16) & 1u);   // RNE; inputs are finite
  return (u16)(u >> 16);
}
__device__ __forceinline__ float bf2f(u16 s) {
  return __builtin_bit_cast(float, (unsigned)s << 16);
}

// ------- fused f32->bf16 convert + dual write (normal layout + transposed) -------
__global__ __launch_bounds__(256) void cvt_dual(const float* __restrict__ src,
                                                u16* __restrict__ dstN,
                                                u16* __restrict__ dstT,
                                                long src_bs, long dstT_bs) {
  __shared__ u16 tile[64][72];
  long bz = blockIdx.z;
  const float* S = src + bz * src_bs;
  u16* DN = dstN + bz * src_bs;
  u16* DT = dstT + bz * dstT_bs;
  int r0 = blockIdx.x * 64;
  int c0 = blockIdx.y * 64;
  int t  = threadIdx.x;
  int tr = t >> 2;
  int tc = (t & 3) * 16;
  const float* sp = &S[(long)(r0 + tr) * 512 + c0 + tc];
#pragma unroll
  for (int q = 0; q < 2; ++q) {
    f32v4 a = *(const f32v4*)(sp + q * 8);
    f32v4 b = *(const f32v4*)(sp + q * 8 + 4);
    u16v8 o;
    o[0] = f2bf(a[0]); o[1] = f2bf(a[1]); o[2] = f2bf(a[2]); o[3] = f2bf(a[3]);
    o[4] = f2bf(b[0]); o[5] = f2bf(b[1]); o[6] = f2bf(b[2]); o[7] = f2bf(b[3]);
    *(u16v8*)&DN[(long)(r0 + tr) * 512 + c0 + tc + q * 8] = o;
    *(u16v8*)&tile[tr][tc + q * 8] = o;
  }
  __syncthreads();
  int tr2 = t >> 3;
  int tc2 = (t & 7) * 8;
#pragma unroll
  for (int it = 0; it < 2; ++it) {
    int cr = it * 32 + tr2;
    u16v8 o;
#pragma unroll
    for (int j = 0; j < 8; ++j) o[j] = tile[tc2 + j][cr];
    *(u16v8*)&DT[(long)(c0 + cr) * 6144 + r0 + tc2] = o;
  }
}

// ------- all weight prep in ONE dispatch -------
__global__ __launch_bounds__(256) void prep_weights(
    const float* __restrict__ Wc, const float* __restrict__ Wa,
    const float* __restrict__ Wk, const float* __restrict__ Wv,
    const float* __restrict__ Wo,
    u16* __restrict__ wc, u16* __restrict__ wa, u16* __restrict__ wk,
    u16* __restrict__ wv, u16* __restrict__ wvT, u16* __restrict__ wo) {
  __shared__ u16 tile[64][72];
  int bx = blockIdx.x;
  int t = threadIdx.x;
  if (bx < 576) {
    const float* src; u16* dst; long base;
    if (bx < 192)      { src = Wc; dst = wc; base = (long)bx * 2048; }
    else if (bx < 320) { src = Wa; dst = wa; base = (long)(bx - 192) * 2048; }
    else if (bx < 448) { src = Wk; dst = wk; base = (long)(bx - 320) * 2048; }
    else               { src = Wo; dst = wo; base = (long)(bx - 448) * 2048; }
    long i = base + (long)t * 8;
    f32v4 a = *(const f32v4*)(src + i);
    f32v4 b = *(const f32v4*)(src + i + 4);
    u16v8 o;
    o[0] = f2bf(a[0]); o[1] = f2bf(a[1]); o[2] = f2bf(a[2]); o[3] = f2bf(a[3]);
    o[4] = f2bf(b[0]); o[5] = f2bf(b[1]); o[6] = f2bf(b[2]); o[7] = f2bf(b[3]);
    *(u16v8*)(dst + i) = o;
  } else {
    int b2 = bx - 576;
    int r0 = (b2 >> 3) * 64, c0 = (b2 & 7) * 64;
    int tr = t >> 2, tc = (t & 3) * 16;
    const float* sp = &Wv[(long)(r0 + tr) * 512 + c0 + tc];
#pragma unroll
    for (int q = 0; q < 2; ++q) {
      f32v4 a = *(const f32v4*)(sp + q * 8);
      f32v4 b = *(const f32v4*)(sp + q * 8 + 4);
      u16v8 o;
      o[0] = f2bf(a[0]); o[1] = f2bf(a[1]); o[2] = f2bf(a[2]); o[3] = f2bf(a[3]);
      o[4] = f2bf(b[0]); o[5] = f2bf(b[1]); o[6] = f2bf(b[2]); o[7] = f2bf(b[3]);
      *(u16v8*)&wv[(long)(r0 + tr) * 512 + c0 + tc + q * 8] = o;
      *(u16v8*)&tile[tr][tc + q * 8] = o;
    }
    __syncthreads();
    int tr2 = t >> 3, tc2 = (t & 7) * 8;
#pragma unroll
    for (int it = 0; it < 2; ++it) {
      int cr = it * 32 + tr2;
      u16v8 o;
#pragma unroll
      for (int j = 0; j < 8; ++j) o[j] = tile[tc2 + j][cr];
      *(u16v8*)&wvT[(long)(c0 + cr) * 512 + r0 + tc2] = o;
    }
  }
}

// -------- reduce 8 split-K bf16 slices -> bf16 (per batch 512x512) --------
__global__ __launch_bounds__(256) void reduce8_bf16(const u16* __restrict__ parts,
                                                    u16* __restrict__ out) {
  long i = (((long)blockIdx.x * 256) + threadIdx.x) * 8;
  long b = i >> 18;
  long r = i & 262143;
  const u16* p = parts + b * 2097152 + r;
  float acc[8] = {};
#pragma unroll
  for (int s = 0; s < 8; ++s) {
    u16v8 v = *(const u16v8*)(p + (long)s * 262144);
#pragma unroll
    for (int j = 0; j < 8; ++j) acc[j] += bf2f(v[j]);
  }
  u16v8 o;
#pragma unroll
  for (int j = 0; j < 8; ++j) o[j] = f2bf(acc[j]);
  *(u16v8*)(out + i) = o;
}

// ------------- NT GEMM 128x128, dbuf + COUNTED vmcnt (T3+T4) -------------
// Used for Gram. LDS 64KB -> 2 blocks/CU. 8 VMEM ops/tile -> vmcnt(8).
// LDS layout: As0 @0, As1 @16384, Bs0 @32768, Bs1 @49152
template <int MODE>
__global__ __launch_bounds__(256) void gemm_nt(
    const u16* __restrict__ A, const u16* __restrict__ B, void* __restrict__ Cout,
    const float* __restrict__ Res, int K, int lda, int ldb, int ldc,
    long sA, long sB, long sC, long sS, long sRes, int kslices) {
  __shared__ __align__(16) char smem_c[65536];

  int gx = gridDim.x, gy = gridDim.y;
  int nwg = gx * gy * (int)gridDim.z;
  int flat = blockIdx.x + gx * (blockIdx.y + gy * blockIdx.z);
  if ((nwg & 7) == 0) { int q = nwg >> 3; flat = (flat & 7) * q + (flat >> 3); }
  int bx = flat % gx; int tmp = flat / gx; int by = tmp % gy; int z = tmp / gy;

  int b = z / kslices;
  int s = z - b * kslices;
  const u16* Ag = A + (long)b * sA + (long)s * K;
  const u16* Bg = B + (long)b * sB + (long)s * K;

  long m0 = (long)bx * 128;
  long n0 = (long)by * 128;

  int tid  = threadIdx.x;
  int lane = tid & 63;
  int wid  = tid >> 6;
  int wm = wid >> 1, wn = wid & 1;

  int srow = wid * 8 + (lane >> 3);
  int scol = (lane & 7) * 8;

  auto stageA = [&](u16* Asd, int k0) {
#pragma unroll
    for (int c = 0; c < 4; ++c) {
      int row = c * 32 + srow;
      __builtin_amdgcn_global_load_lds(
          (const __attribute__((address_space(1))) void*)(Ag + (m0 + row) * lda + k0 + scol),
          (__attribute__((address_space(3))) void*)(Asd + (c * 32 + wid * 8) * 64),
          16, 0, 0);
    }
  };
  auto stageB = [&](u16* Bsd, int k0) {
#pragma unroll
    for (int c = 0; c < 4; ++c) {
      int row = c * 32 + srow;
      __builtin_amdgcn_global_load_lds(
          (const __attribute__((address_space(1))) void*)(Bg + (n0 + row) * ldb + k0 + scol),
          (__attribute__((address_space(3))) void*)(Bsd + (c * 32 + wid * 8) * 64),
          16, 0, 0);
    }
  };

  f32x4 acc[4][4] = {};
  int nk = K >> 6;

  stageA((u16*)smem_c, 0);
  stageB((u16*)(smem_c + 32768), 0);

  for (int t = 0; t < nk; ++t) {
    u16* Asc = (u16*)(smem_c + (t & 1) * 16384);
    u16* Bsc = (u16*)(smem_c + 32768 + (t & 1) * 16384);
    if (t + 1 < nk) {
      u16* Asn = (u16*)(smem_c + ((t + 1) & 1) * 16384);
      u16* Bsn = (u16*)(smem_c + 32768 + ((t + 1) & 1) * 16384);
      stageA(Asn, (t + 1) * 64);
      stageB(Bsn, (t + 1) * 64);
      asm volatile("s_waitcnt vmcnt(8)\n\ts_barrier" ::: "memory");
    } else {
      asm volatile("s_waitcnt vmcnt(0)\n\ts_barrier" ::: "memory");
    }
#pragma unroll
    for (int kk = 0; kk < 2; ++kk) {
      int kofs = kk * 32 + (lane >> 4) * 8;
      bf16x8 af[4], bfr[4];
#pragma unroll
      for (int i = 0; i < 4; ++i) {
        af[i]  = *(const bf16x8*)&Asc[(wm * 64 + i * 16 + (lane & 15)) * 64 + kofs];
        bfr[i] = *(const bf16x8*)&Bsc[(wn * 64 + i * 16 + (lane & 15)) * 64 + kofs];
      }
#pragma unroll
      for (int i = 0; i < 4; ++i)
#pragma unroll
        for (int j = 0; j < 4; ++j)
          acc[i][j] = __builtin_amdgcn_mfma_f32_16x16x32_bf16(af[i], bfr[j], acc[i][j], 0, 0, 0);
    }
    asm volatile("s_barrier" ::: "memory");   // reads done before next stage overwrites
  }

  float* ep = (float*)(smem_c + wid * 4608);
  long cb  = (long)b * sC + (long)s * sS;
  int row0 = (int)m0 + wm * 64;
  int colb = (int)n0 + wn * 64;
  int lq = lane >> 4;
  int lr = lane & 15;

#pragma unroll
  for (int i = 0; i < 4; ++i) {
#pragma unroll
    for (int j = 0; j < 4; ++j)
#pragma unroll
      for (int r = 0; r < 4; ++r)
        ep[(lq * 4 + r) * 72 + lr + j * 16] = acc[i][j][r];
#pragma unroll
    for (int p = 0; p < 4; ++p) {
      int rl = p * 4 + lq;
      f32x4 v = *(f32x4*)&ep[rl * 72 + lr * 4];
      long off = (long)(row0 + i * 16 + rl) * ldc + colb + lr * 4;
      if (MODE == 0) {
        u16v4 o;
#pragma unroll
        for (int t2 = 0; t2 < 4; ++t2) o[t2] = f2bf(v[t2]);
        *(u16v4*)((u16*)Cout + cb + off) = o;
      } else {
        const float* R = Res + (long)b * sRes;
        f32v4 rv = *(const f32v4*)&R[off];
        f32v4 ov;
#pragma unroll
        for (int t2 = 0; t2 < 4; ++t2) ov[t2] = v[t2] + rv[t2];
        *(f32v4*)((float*)Cout + cb + off) = ov;
      }
    }
  }
}

// ------------- NT GEMM 64x128, dbuf + COUNTED vmcnt (T3+T4) -------------
// LDS 48KB -> 3 blocks/CU. 6 VMEM/tile (bf16) -> vmcnt(6); AF32: 8 -> vmcnt(8).
// MODE: 0=bf16, 1=f32+residual, 3=bf16 transposed store.
// LDS layout: As0 @0 (8KB), As1 @8192, Bs0 @16384 (16KB), Bs1 @32768
template <int MODE, bool AF32>
__global__ __launch_bounds__(256) void gemm64(
    const void* __restrict__ Ap, const u16* __restrict__ B, void* __restrict__ Cout,
    const float* __restrict__ Res, int K, int lda, int ldb, int ldc,
    long sA, long sB, long sC, long sRes) {
  __shared__ __align__(16) char smem_c[49152];

  int gx = gridDim.x, gy = gridDim.y;
  int nwg = gx * gy * (int)gridDim.z;
  int flat = blockIdx.x + gx * (blockIdx.y + gy * blockIdx.z);
  if ((nwg & 7) == 0) { int q = nwg >> 3; flat = (flat & 7) * q + (flat >> 3); }
  int bx = flat % gx; int tmp = flat / gx; int by = tmp % gy; int b = tmp / gy;

  long n0 = (long)bx * 128;
  long m0 = (long)by * 64;
  const u16* Ag = (const u16*)Ap + (long)b * sA;
  const float* Af = (const float*)Ap + (long)b * sA;
  const u16* Bg = B + (long)b * sB;

  int tid  = threadIdx.x;
  int lane = tid & 63;
  int wid  = tid >> 6;
  int wm = wid >> 1, wn = wid & 1;

  int srow = wid * 8 + (lane >> 3);
  int scol = (lane & 7) * 8;
  int arow = tid >> 2;            // AF32: 0..63
  int acol = (tid & 3) * 16;      // AF32: f32 col

  auto stageA = [&](u16* Asd, int k0) {
#pragma unroll
    for (int c = 0; c < 2; ++c) {
      int row = c * 32 + srow;
      __builtin_amdgcn_global_load_lds(
          (const __attribute__((address_space(1))) void*)(Ag + (m0 + row) * lda + k0 + scol),
          (__attribute__((address_space(3))) void*)(Asd + (c * 32 + wid * 8) * 64),
          16, 0, 0);
    }
  };
  auto stageB = [&](u16* Bsd, int k0) {
#pragma unroll
    for (int c = 0; c < 4; ++c) {
      int row = c * 32 + srow;
      __builtin_amdgcn_global_load_lds(
          (const __attribute__((address_space(1))) void*)(Bg + (n0 + row) * ldb + k0 + scol),
          (__attribute__((address_space(3))) void*)(Bsd + (c * 32 + wid * 8) * 64),
          16, 0, 0);
    }
  };
  auto cvtA = [&](u16* Asd, const f32v4& x0, const f32v4& x1,
                  const f32v4& x2, const f32v4& x3) {
    u16v8 o0, o1;
    o0[0] = f2bf(x0[0]); o0[1] = f2bf(x0[1]); o0[2] = f2bf(x0[2]); o0[3] = f2bf(x0[3]);
    o0[4] = f2bf(x1[0]); o0[5] = f2bf(x1[1]); o0[6] = f2bf(x1[2]); o0[7] = f2bf(x1[3]);
    o1[0] = f2bf(x2[0]); o1[1] = f2bf(x2[1]); o1[2] = f2bf(x2[2]); o1[3] = f2bf(x2[3]);
    o1[4] = f2bf(x3[0]); o1[5] = f2bf(x3[1]); o1[6] = f2bf(x3[2]); o1[7] = f2bf(x3[3]);
    *(u16v8*)&Asd[arow * 64 + acol] = o0;
    *(u16v8*)&Asd[arow * 64 + acol + 8] = o1;
  };

  f32x4 acc[2][4] = {};
  int nk = K >> 6;

  // prologue: stage tile 0 into buffer 0
  if constexpr (AF32) {
    const float* sp = Af + (m0 + arow) * (long)lda + acol;
    f32v4 x0 = *(const f32v4*)sp;
    f32v4 x1 = *(const f32v4*)(sp + 4);
    f32v4 x2 = *(const f32v4*)(sp + 8);
    f32v4 x3 = *(const f32v4*)(sp + 12);
    cvtA((u16*)smem_c, x0, x1, x2, x3);
    asm volatile("s_waitcnt lgkmcnt(0)" ::: "memory");  // ds_writes visible before barrier A
  } else {
    stageA((u16*)smem_c, 0);
  }
  stageB((u16*)(smem_c + 16384), 0);

  for (int t = 0; t < nk; ++t) {
    u16* Asc = (u16*)(smem_c + (t & 1) * 8192);
    u16* Bsc = (u16*)(smem_c + 16384 + (t & 1) * 16384);
    u16* Asn = (u16*)(smem_c + ((t + 1) & 1) * 8192);
    u16* Bsn = (u16*)(smem_c + 16384 + ((t + 1) & 1) * 16384);
    bool more = (t + 1) < nk;
    f32v4 x0, x1, x2, x3;
    if (more) {
      if constexpr (AF32) {
        const float* sp = Af + (m0 + arow) * (long)lda + (t + 1) * 64 + acol;
        x0 = *(const f32v4*)sp;
        x1 = *(const f32v4*)(sp + 4);
        x2 = *(const f32v4*)(sp + 8);
        x3 = *(const f32v4*)(sp + 12);
        stageB(Bsn, (t + 1) * 64);
        asm volatile("s_waitcnt vmcnt(8)\n\ts_barrier" ::: "memory");
      } else {
        stageA(Asn, (t + 1) * 64);
        stageB(Bsn, (t + 1) * 64);
        asm volatile("s_waitcnt vmcnt(6)\n\ts_barrier" ::: "memory");
      }
    } else {
      asm volatile("s_waitcnt vmcnt(0)\n\ts_barrier" ::: "memory");
    }
#pragma unroll
    for (int kk = 0; kk < 2; ++kk) {
      int kofs = kk * 32 + (lane >> 4) * 8;
      bf16x8 af[2], bfr[4];
#pragma unroll
      for (int i = 0; i < 2; ++i)
        af[i]  = *(const bf16x8*)&Asc[(wm * 32 + i * 16 + (lane & 15)) * 64 + kofs];
#pragma unroll
      for (int j = 0; j < 4; ++j)
        bfr[j] = *(const bf16x8*)&Bsc[(wn * 64 + j * 16 + (lane & 15)) * 64 + kofs];
#pragma unroll
      for (int i = 0; i < 2; ++i)
#pragma unroll
        for (int j = 0; j < 4; ++j)
          acc[i][j] = __builtin_amdgcn_mfma_f32_16x16x32_bf16(af[i], bfr[j], acc[i][j], 0, 0, 0);
    }
    if constexpr (AF32) {
      if (more) cvtA(Asn, x0, x1, x2, x3);
      asm volatile("s_waitcnt lgkmcnt(0)\n\ts_barrier" ::: "memory");
    } else {
      asm volatile("s_barrier" ::: "memory");
    }
  }

  int lq = lane >> 4;
  int lr = lane & 15;

  if (MODE == 0 || MODE == 1) {
    float* ep = (float*)(smem_c + wid * 4608);   // wave-private scratch
    long cb  = (long)b * sC;
    int row0 = (int)m0 + wm * 32;
    int colb = (int)n0 + wn * 64;
#pragma unroll
    for (int i = 0; i < 2; ++i) {
#pragma unroll
      for (int j = 0; j < 4; ++j)
#pragma unroll
        for (int r = 0; r < 4; ++r)
          ep[(lq * 4 + r) * 72 + lr + j * 16] = acc[i][j][r];
#pragma unroll
      for (int p = 0; p < 4; ++p) {
        int rl = p * 4 + lq;
        f32x4 v = *(f32x4*)&ep[rl * 72 + lr * 4];
        long off = (long)(row0 + i * 16 + rl) * ldc + colb + lr * 4;
        if (MODE == 0) {
          u16v4 o;
#pragma unroll
          for (int t2 = 0; t2 < 4; ++t2) o[t2] = f2bf(v[t2]);
          *(u16v4*)((u16*)Cout + cb + off) = o;
        } else {
          const float* R = Res + (long)b * sRes;
          f32v4 rv = *(const f32v4*)&R[off];
          f32v4 ov;
#pragma unroll
          for (int t2 = 0; t2 < 4; ++t2) ov[t2] = v[t2] + rv[t2];
          *(f32v4*)((float*)Cout + cb + off) = ov;
        }
      }
    }
  } else {
    // MODE 3: transposed bf16 store via LDS [128][72] (after final barrier: safe)
    u16* tT = (u16*)smem_c;
#pragma unroll
    for (int i = 0; i < 2; ++i)
#pragma unroll
      for (int j = 0; j < 4; ++j)
#pragma unroll
        for (int r = 0; r < 4; ++r)
          tT[(wn * 64 + j * 16 + lr) * 72 + wm * 32 + i * 16 + lq * 4 + r] = f2bf(acc[i][j][r]);
    __syncthreads();
    long cb = (long)b * sC;
    int ct  = tid >> 1;
    int seg = (tid & 1) * 32;
    u16* dst = (u16*)Cout + cb + (long)(n0 + ct) * ldc + m0 + seg;
    const u16* srcl = &tT[ct * 72 + seg];
#pragma unroll
    for (int q = 0; q < 4; ++q)
      *(u16v8*)(dst + q * 8) = *(const u16v8*)(srcl + q * 8);
  }
}

// ------- logits GEMM with FUSED channel softmax: attn = softmax(h_bf @ Wa^T) -------
__global__ __launch_bounds__(256, 2) void gemm_sm(
    const u16* __restrict__ A,    // [32768 x 512] bf16
    const u16* __restrict__ Bw,   // [512 x 512] bf16 (w_attn)
    u16* __restrict__ C) {        // [32768 x 512] bf16 attn
  __shared__ __align__(16) char smem[73728];
  u16* As = (u16*)smem;                 // [64][64]
  u16* Bs = (u16*)(smem + 8192);        // [512][64]

  int nwg = gridDim.x;
  int flat = blockIdx.x;
  if ((nwg & 7) == 0) { int q = nwg >> 3; flat = (flat & 7) * q + (flat >> 3); }
  long m0 = (long)flat * 64;

  int tid = threadIdx.x;
  int lane = tid & 63;
  int wid = tid >> 6;

  int srow = wid * 8 + (lane >> 3);
  int scol = (lane & 7) * 8;

  f32x4 acc[4][8] = {};

  for (int k0 = 0; k0 < 512; k0 += 64) {
#pragma unroll
    for (int c = 0; c < 2; ++c) {
      int row = c * 32 + srow;
      __builtin_amdgcn_global_load_lds(
          (const __attribute__((address_space(1))) void*)(A + (m0 + row) * 512 + k0 + scol),
          (__attribute__((address_space(3))) void*)(As + (c * 32 + wid * 8) * 64),
          16, 0, 0);
    }
#pragma unroll
    for (int c = 0; c < 16; ++c) {
      int row = c * 32 + srow;
      __builtin_amdgcn_global_load_lds(
          (const __attribute__((address_space(1))) void*)(Bw + (long)row * 512 + k0 + scol),
          (__attribute__((address_space(3))) void*)(Bs + (c * 32 + wid * 8) * 64),
          16, 0, 0);
    }
    __syncthreads();
#pragma unroll
    for (int kk = 0; kk < 2; ++kk) {
      int kofs = kk * 32 + (lane >> 4) * 8;
      bf16x8 af[4], bfr[8];
#pragma unroll
      for (int i = 0; i < 4; ++i)
        af[i] = *(const bf16x8*)&As[(i * 16 + (lane & 15)) * 64 + kofs];
#pragma unroll
      for (int j = 0; j < 8; ++j)
        bfr[j] = *(const bf16x8*)&Bs[(wid * 128 + j * 16 + (lane & 15)) * 64 + kofs];
#pragma unroll
      for (int i = 0; i < 4; ++i)
#pragma unroll
        for (int j = 0; j < 8; ++j)
          acc[i][j] = __builtin_amdgcn_mfma_f32_16x16x32_bf16(af[i], bfr[j], acc[i][j], 0, 0, 0);
    }
    __syncthreads();
  }

  int lq = lane >> 4, lr = lane & 15;
  float* sm = (float*)smem;            // [64][4]
  float* ss = (float*)(smem + 1024);   // [64][4]

#pragma unroll
  for (int i = 0; i < 4; ++i)
#pragma unroll
    for (int r = 0; r < 4; ++r) {
      float m = acc[i][0][r];
#pragma unroll
      for (int j = 1; j < 8; ++j) m = fmaxf(m, acc[i][j][r]);
#pragma unroll
      for (int o = 1; o < 16; o <<= 1) m = fmaxf(m, __shfl_xor(m, o, 16));
      if (lr == 0) sm[(i * 16 + lq * 4 + r) * 4 + wid] = m;
    }
  __syncthreads();
  float rinv[4][4];
#pragma unroll
  for (int i = 0; i < 4; ++i)
#pragma unroll
    for (int r = 0; r < 4; ++r) {
      f32v4 g4 = *(const f32v4*)&sm[(i * 16 + lq * 4 + r) * 4];
      float gm = fmaxf(fmaxf(g4[0], g4[1]), fmaxf(g4[2], g4[3]));
      float s = 0.f;
#pragma unroll
      for (int j = 0; j < 8; ++j) {
        float e = __expf(acc[i][j][r] - gm);
        acc[i][j][r] = e;
        s += e;
      }
#pragma unroll
      for (int o = 1; o < 16; o <<= 1) s += __shfl_xor(s, o, 16);
      if (lr == 0) ss[(i * 16 + lq * 4 + r) * 4 + wid] = s;
    }
  __syncthreads();
#pragma unroll
  for (int i = 0; i < 4; ++i)
#pragma unroll
    for (int r = 0; r < 4; ++r) {
      f32v4 g4 = *(const f32v4*)&ss[(i * 16 + lq * 4 + r) * 4];
      rinv[i][r] = 1.0f / (g4[0] + g4[1] + g4[2] + g4[3]);
    }
  __syncthreads();

  float* ep = (float*)(smem + wid * 4608);
#pragma unroll
  for (int i = 0; i < 4; ++i) {
#pragma unroll
    for (int jh = 0; jh < 2; ++jh) {
#pragma unroll
      for (int j = 0; j < 4; ++j)
#pragma unroll
        for (int r = 0; r < 4; ++r)
          ep[(lq * 4 + r) * 72 + lr + j * 16] = acc[i][jh * 4 + j][r] * rinv[i][r];
#pragma unroll
      for (int p = 0; p < 4; ++p) {
        int rl = p * 4 + lq;
        f32x4 v = *(f32x4*)&ep[rl * 72 + lr * 4];
        u16v4 o;
#pragma unroll
        for (int t = 0; t < 4; ++t) o[t] = f2bf(v[t]);
        *(u16v4*)&C[(m0 + i * 16 + rl) * 512 + wid * 128 + jh * 64 + lr * 4] = o;
      }
    }
  }
}

// ---------------- host ----------------
extern "C" void kernel_launch(void* const* d_in, const int* in_sizes, int n_in,
                              void* d_out, int out_size, void* d_ws, size_t ws_size,
                              hipStream_t stream) {
  (void)in_sizes; (void)n_in; (void)out_size; (void)ws_size;
  const float* h    = (const float*)d_in[0];
  const float* hret = (const float*)d_in[1];
  const float* Wc   = (const float*)d_in[2];
  const float* Wa   = (const float*)d_in[3];
  const float* Wk   = (const float*)d_in[4];
  const float* Wv   = (const float*)d_in[5];
  const float* Wo   = (const float*)d_in[6];
  float* out = (float*)d_out;
  char*  ws  = (char*)d_ws;

  constexpr long MB = 1024 * 1024;
  u16*   w_cond = (u16*)(ws + 0);
  u16*   w_attn = (u16*)(ws + 786432);
  u16*   w_k    = (u16*)(ws + 1310720);
  u16*   w_v    = (u16*)(ws + 1835008);
  u16*   w_out  = (u16*)(ws + 2359296);
  u16*   w_vT   = (u16*)(ws + 2883584);
  u16*   h_bf   = (u16*)(ws + 4 * MB);
  u16*   gparts = (u16*)(ws + 4 * MB);    // overlay h_bf (dead after gemm_sm)
  u16*   attn   = (u16*)(ws + 36 * MB);
  u16*   g_bf   = (u16*)(ws + 68 * MB);
  u16*   u_mat  = (u16*)(ws + 72 * MB);
  u16*   v1     = (u16*)(ws + 73 * MB);
  u16*   f2t    = (u16*)(ws + 77 * MB);
  u16*   xt     = (u16*)(ws + 84 * MB);

  // 1) h: fused convert + transpose  (h_bf rows + xt[:, 0:4096])
  cvt_dual<<<dim3(64, 8, 8), 256, 0, stream>>>(h, h_bf, xt, 2097152L, 3145728L);
  // 2) all weights in one dispatch
  prep_weights<<<640, 256, 0, stream>>>(Wc, Wa, Wk, Wv, Wo,
      w_cond, w_attn, w_k, w_v, w_vT, w_out);

  // 3) hr = hret(f32) @ W_cond^T, reg-staged convert, written TRANSPOSED into xt[:, 4096:6144]
  gemm64<3, true><<<dim3(4, 32, 8), 256, 0, stream>>>(hret, w_cond, xt + 4096, nullptr,
      768, 768, 768, 6144, 1572864L, 0, 3145728L, 0);

  // 4) attn = softmax(h_bf @ W_attn^T) fused, all batches flat (M=32768)
  gemm_sm<<<512, 256, 0, stream>>>(h_bf, w_attn, attn);

  // 5) Gram G = X^T X via NT(xt, xt), split-K=8 bf16 partials, reduce -> bf16
  gemm_nt<0><<<dim3(4, 4, 64), 256, 0, stream>>>(xt, xt, gparts, nullptr,
      768, 6144, 6144, 512, 3145728L, 3145728L, 2097152L, 262144L, 0, 8);
  reduce8_bf16<<<1024, 256, 0, stream>>>(gparts, g_bf);

  // 6) f2^T = W_out W_v G W_k^T (G symmetric):
  gemm64<0, false><<<dim3(4, 8, 1), 256, 0, stream>>>(w_out, w_vT, u_mat, nullptr,
      512, 512, 512, 512, 0, 0, 0, 0);
  gemm64<0, false><<<dim3(4, 8, 8), 256, 0, stream>>>(u_mat, g_bf, v1, nullptr,
      512, 512, 512, 512, 0, 262144L, 262144L, 0);
  gemm64<0, false><<<dim3(4, 8, 8), 256, 0, stream>>>(v1, w_k, f2t, nullptr,
      512, 512, 512, 512, 262144L, 0, 262144L, 0);

  // 7) out = h + attn @ f2  (fused residual, f32 out)
  gemm64<1, false><<<dim3(4, 64, 8), 256, 0, stream>>>(attn, f2t, out, h,
      512, 512, 512, 512, 2097152L, 262144L, 2097152L, 2097152L);
}

// Round 8
// 210.276 us; speedup vs baseline: 1.3006x; 1.0172x over previous
//
#include <hip/hip_runtime.h>
#include <hip/hip_bf16.h>

// Problem: B=8, N=4096, M=2048, IN=512, D=512, CTX=768
// out = h + attn @ f2,  attn = softmax(h W_a^T),  f2^T = W_out W_v G W_k^T,
// G = X^T X (symmetric), X = [h; h_retrieved W_c^T]  (all bf16 MFMA internally)

typedef unsigned short u16;
typedef __bf16 bf16x8 __attribute__((ext_vector_type(8)));
typedef float  f32x4  __attribute__((ext_vector_type(4)));
typedef float  f32v4  __attribute__((ext_vector_type(4)));
typedef u16    u16v4  __attribute__((ext_vector_type(4)));
typedef u16    u16v8  __attribute__((ext_vector_type(8)));

__device__ __forceinline__ u16 f2bf(float f) {
  unsigned u = __builtin_bit_cast(unsigned, f);
  u = u + 0x7FFFu + ((u >> 16) & 1u);   // RNE; inputs are finite
  return (u16)(u >> 16);
}
__device__ __forceinline__ float bf2f(u16 s) {
  return __builtin_bit_cast(float, (unsigned)s << 16);
}

// ------- f32 -> bf16 transpose only: xt[b][c][r] = bf16(h[b][r][c]) -------
__global__ __launch_bounds__(256) void cvt_T(const float* __restrict__ src,
                                             u16* __restrict__ dstT,
                                             long src_bs, long dstT_bs) {
  __shared__ u16 tile[64][72];
  long bz = blockIdx.z;
  const float* S = src + bz * src_bs;
  u16* DT = dstT + bz * dstT_bs;
  int r0 = blockIdx.x * 64;
  int c0 = blockIdx.y * 64;
  int t  = threadIdx.x;
  int tr = t >> 2;
  int tc = (t & 3) * 16;
  const float* sp = &S[(long)(r0 + tr) * 512 + c0 + tc];
#pragma unroll
  for (int q = 0; q < 2; ++q) {
    f32v4 a = *(const f32v4*)(sp + q * 8);
    f32v4 b = *(const f32v4*)(sp + q * 8 + 4);
    u16v8 o;
    o[0] = f2bf(a[0]); o[1] = f2bf(a[1]); o[2] = f2bf(a[2]); o[3] = f2bf(a[3]);
    o[4] = f2bf(b[0]); o[5] = f2bf(b[1]); o[6] = f2bf(b[2]); o[7] = f2bf(b[3]);
    *(u16v8*)&tile[tr][tc + q * 8] = o;
  }
  __syncthreads();
  int tr2 = t >> 3;
  int tc2 = (t & 7) * 8;
#pragma unroll
  for (int it = 0; it < 2; ++it) {
    int cr = it * 32 + tr2;
    u16v8 o;
#pragma unroll
    for (int j = 0; j < 8; ++j) o[j] = tile[tc2 + j][cr];
    *(u16v8*)&DT[(long)(c0 + cr) * 6144 + r0 + tc2] = o;
  }
}

// ------- all weight prep in ONE dispatch -------
__global__ __launch_bounds__(256) void prep_weights(
    const float* __restrict__ Wc, const float* __restrict__ Wa,
    const float* __restrict__ Wk, const float* __restrict__ Wv,
    const float* __restrict__ Wo,
    u16* __restrict__ wc, u16* __restrict__ wa, u16* __restrict__ wk,
    u16* __restrict__ wv, u16* __restrict__ wvT, u16* __restrict__ wo) {
  __shared__ u16 tile[64][72];
  int bx = blockIdx.x;
  int t = threadIdx.x;
  if (bx < 576) {
    const float* src; u16* dst; long base;
    if (bx < 192)      { src = Wc; dst = wc; base = (long)bx * 2048; }
    else if (bx < 320) { src = Wa; dst = wa; base = (long)(bx - 192) * 2048; }
    else if (bx < 448) { src = Wk; dst = wk; base = (long)(bx - 320) * 2048; }
    else               { src = Wo; dst = wo; base = (long)(bx - 448) * 2048; }
    long i = base + (long)t * 8;
    f32v4 a = *(const f32v4*)(src + i);
    f32v4 b = *(const f32v4*)(src + i + 4);
    u16v8 o;
    o[0] = f2bf(a[0]); o[1] = f2bf(a[1]); o[2] = f2bf(a[2]); o[3] = f2bf(a[3]);
    o[4] = f2bf(b[0]); o[5] = f2bf(b[1]); o[6] = f2bf(b[2]); o[7] = f2bf(b[3]);
    *(u16v8*)(dst + i) = o;
  } else {
    int b2 = bx - 576;
    int r0 = (b2 >> 3) * 64, c0 = (b2 & 7) * 64;
    int tr = t >> 2, tc = (t & 3) * 16;
    const float* sp = &Wv[(long)(r0 + tr) * 512 + c0 + tc];
#pragma unroll
    for (int q = 0; q < 2; ++q) {
      f32v4 a = *(const f32v4*)(sp + q * 8);
      f32v4 b = *(const f32v4*)(sp + q * 8 + 4);
      u16v8 o;
      o[0] = f2bf(a[0]); o[1] = f2bf(a[1]); o[2] = f2bf(a[2]); o[3] = f2bf(a[3]);
      o[4] = f2bf(b[0]); o[5] = f2bf(b[1]); o[6] = f2bf(b[2]); o[7] = f2bf(b[3]);
      *(u16v8*)&wv[(long)(r0 + tr) * 512 + c0 + tc + q * 8] = o;
      *(u16v8*)&tile[tr][tc + q * 8] = o;
    }
    __syncthreads();
    int tr2 = t >> 3, tc2 = (t & 7) * 8;
#pragma unroll
    for (int it = 0; it < 2; ++it) {
      int cr = it * 32 + tr2;
      u16v8 o;
#pragma unroll
      for (int j = 0; j < 8; ++j) o[j] = tile[tc2 + j][cr];
      *(u16v8*)&wvT[(long)(c0 + cr) * 512 + r0 + tc2] = o;
    }
  }
}

// -------- reduce 8 split-K bf16 slices -> bf16 (per batch 512x512) --------
__global__ __launch_bounds__(256) void reduce8_bf16(const u16* __restrict__ parts,
                                                    u16* __restrict__ out) {
  long i = (((long)blockIdx.x * 256) + threadIdx.x) * 8;
  long b = i >> 18;
  long r = i & 262143;
  const u16* p = parts + b * 2097152 + r;
  float acc[8] = {};
#pragma unroll
  for (int s = 0; s < 8; ++s) {
    u16v8 v = *(const u16v8*)(p + (long)s * 262144);
#pragma unroll
    for (int j = 0; j < 8; ++j) acc[j] += bf2f(v[j]);
  }
  u16v8 o;
#pragma unroll
  for (int j = 0; j < 8; ++j) o[j] = f2bf(acc[j]);
  *(u16v8*)(out + i) = o;
}

// ------------- NT GEMM 128x128, dbuf + counted vmcnt -------------
// MODE: 0=bf16 store, 1=f32 store + f32 residual, 3=bf16 TRANSPOSED store,
//       4=bf16 store + mirrored transposed store (symmetric Gram, triangle grid 10 pairs)
// AF32: A is f32 in global; reg-staged convert into LDS (ds_write), vmcnt(12).
// LDS layout: As0 @0, As1 @16384, Bs0 @32768, Bs1 @49152
template <int MODE, bool AF32>
__global__ __launch_bounds__(256) void gemm_nt(
    const void* __restrict__ Ap, const u16* __restrict__ B, void* __restrict__ Cout,
    const float* __restrict__ Res, int K, int lda, int ldb, int ldc,
    long sA, long sB, long sC, long sS, long sRes, int kslices) {
  __shared__ __align__(16) char smem_c[65536];

  int gx = gridDim.x, gy = gridDim.y;
  int nwg = gx * gy * (int)gridDim.z;
  int flat = blockIdx.x + gx * (blockIdx.y + gy * blockIdx.z);
  if ((nwg & 7) == 0) { int q = nwg >> 3; flat = (flat & 7) * q + (flat >> 3); }
  int bx = flat % gx; int tmp = flat / gx; int by = tmp % gy; int z = tmp / gy;

  int b = z / kslices;
  int s = z - b * kslices;

  int mt = bx, nt = by;
  if constexpr (MODE == 4) {   // triangle pair decode: bx in [0,10)
    if (bx < 4)      { mt = 0; nt = bx; }
    else if (bx < 7) { mt = 1; nt = bx - 3; }
    else if (bx < 9) { mt = 2; nt = bx - 5; }
    else             { mt = 3; nt = 3; }
  }
  long m0 = (long)mt * 128;
  long n0 = (long)nt * 128;

  const u16* Ag = (const u16*)Ap + (long)b * sA + (long)s * K;
  const float* Af = (const float*)Ap + (long)b * sA;   // AF32: no split-K use
  const u16* Bg = B + (long)b * sB + (long)s * K;

  int tid  = threadIdx.x;
  int lane = tid & 63;
  int wid  = tid >> 6;
  int wm = wid >> 1, wn = wid & 1;

  int srow = wid * 8 + (lane >> 3);
  int scol = (lane & 7) * 8;
  int arow  = tid >> 1;           // AF32: 0..127
  int acolb = (tid & 1) * 32;     // AF32: f32 col base

  auto stageA = [&](u16* Asd, int k0) {
#pragma unroll
    for (int c = 0; c < 4; ++c) {
      int row = c * 32 + srow;
      __builtin_amdgcn_global_load_lds(
          (const __attribute__((address_space(1))) void*)(Ag + (m0 + row) * lda + k0 + scol),
          (__attribute__((address_space(3))) void*)(Asd + (c * 32 + wid * 8) * 64),
          16, 0, 0);
    }
  };
  auto stageB = [&](u16* Bsd, int k0) {
#pragma unroll
    for (int c = 0; c < 4; ++c) {
      int row = c * 32 + srow;
      __builtin_amdgcn_global_load_lds(
          (const __attribute__((address_space(1))) void*)(Bg + (n0 + row) * ldb + k0 + scol),
          (__attribute__((address_space(3))) void*)(Bsd + (c * 32 + wid * 8) * 64),
          16, 0, 0);
    }
  };
  f32v4 xr[8];
  auto loadA = [&](int k0) {
    const float* sp = Af + (m0 + arow) * (long)lda + k0 + acolb;
#pragma unroll
    for (int q = 0; q < 8; ++q) xr[q] = *(const f32v4*)(sp + q * 4);
  };
  auto cvtA = [&](u16* Asd) {
#pragma unroll
    for (int q = 0; q < 4; ++q) {
      u16v8 o;
      o[0] = f2bf(xr[2*q][0]); o[1] = f2bf(xr[2*q][1]);
      o[2] = f2bf(xr[2*q][2]); o[3] = f2bf(xr[2*q][3]);
      o[4] = f2bf(xr[2*q+1][0]); o[5] = f2bf(xr[2*q+1][1]);
      o[6] = f2bf(xr[2*q+1][2]); o[7] = f2bf(xr[2*q+1][3]);
      *(u16v8*)&Asd[arow * 64 + acolb + q * 8] = o;
    }
  };

  f32x4 acc[4][4] = {};
  int nk = K >> 6;

  if constexpr (AF32) {
    loadA(0);
    cvtA((u16*)smem_c);
    asm volatile("s_waitcnt lgkmcnt(0)" ::: "memory");
  } else {
    stageA((u16*)smem_c, 0);
  }
  stageB((u16*)(smem_c + 32768), 0);

  for (int t = 0; t < nk; ++t) {
    u16* Asc = (u16*)(smem_c + (t & 1) * 16384);
    u16* Bsc = (u16*)(smem_c + 32768 + (t & 1) * 16384);
    u16* Asn = (u16*)(smem_c + ((t + 1) & 1) * 16384);
    u16* Bsn = (u16*)(smem_c + 32768 + ((t + 1) & 1) * 16384);
    bool more = (t + 1) < nk;
    if (more) {
      if constexpr (AF32) {
        loadA((t + 1) * 64);
        stageB(Bsn, (t + 1) * 64);
        asm volatile("s_waitcnt vmcnt(12)\n\ts_barrier" ::: "memory");
      } else {
        stageA(Asn, (t + 1) * 64);
        stageB(Bsn, (t + 1) * 64);
        asm volatile("s_waitcnt vmcnt(8)\n\ts_barrier" ::: "memory");
      }
    } else {
      asm volatile("s_waitcnt vmcnt(0)\n\ts_barrier" ::: "memory");
    }
#pragma unroll
    for (int kk = 0; kk < 2; ++kk) {
      int kofs = kk * 32 + (lane >> 4) * 8;
      bf16x8 af[4], bfr[4];
#pragma unroll
      for (int i = 0; i < 4; ++i) {
        af[i]  = *(const bf16x8*)&Asc[(wm * 64 + i * 16 + (lane & 15)) * 64 + kofs];
        bfr[i] = *(const bf16x8*)&Bsc[(wn * 64 + i * 16 + (lane & 15)) * 64 + kofs];
      }
#pragma unroll
      for (int i = 0; i < 4; ++i)
#pragma unroll
        for (int j = 0; j < 4; ++j)
          acc[i][j] = __builtin_amdgcn_mfma_f32_16x16x32_bf16(af[i], bfr[j], acc[i][j], 0, 0, 0);
    }
    if constexpr (AF32) {
      if (more) cvtA(Asn);
      asm volatile("s_waitcnt lgkmcnt(0)\n\ts_barrier" ::: "memory");
    } else {
      asm volatile("s_barrier" ::: "memory");
    }
  }

  long cb = (long)b * sC + (long)s * sS;
  int lq = lane >> 4;
  int lr = lane & 15;

  if constexpr (MODE == 0 || MODE == 1 || MODE == 4) {
    float* ep = (float*)(smem_c + wid * 4608);   // wave-private
    int row0 = (int)m0 + wm * 64;
    int colb = (int)n0 + wn * 64;
#pragma unroll
    for (int i = 0; i < 4; ++i) {
#pragma unroll
      for (int j = 0; j < 4; ++j)
#pragma unroll
        for (int r = 0; r < 4; ++r)
          ep[(lq * 4 + r) * 72 + lr + j * 16] = acc[i][j][r];
#pragma unroll
      for (int p = 0; p < 4; ++p) {
        int rl = p * 4 + lq;
        f32x4 v = *(f32x4*)&ep[rl * 72 + lr * 4];
        long off = (long)(row0 + i * 16 + rl) * ldc + colb + lr * 4;
        if (MODE == 0 || MODE == 4) {
          u16v4 o;
#pragma unroll
          for (int t2 = 0; t2 < 4; ++t2) o[t2] = f2bf(v[t2]);
          *(u16v4*)((u16*)Cout + cb + off) = o;
        } else {
          const float* R = Res + (long)b * sRes;
          f32v4 rv = *(const f32v4*)&R[off];
          f32v4 ov;
#pragma unroll
          for (int t2 = 0; t2 < 4; ++t2) ov[t2] = v[t2] + rv[t2];
          *(f32v4*)((float*)Cout + cb + off) = ov;
        }
      }
    }
    if constexpr (MODE == 4) {
      if (mt != nt) {   // block-uniform
        u16* tT = (u16*)(smem_c + 18432);   // [128][136] u16
#pragma unroll
        for (int i = 0; i < 4; ++i)
#pragma unroll
          for (int j = 0; j < 4; ++j)
#pragma unroll
            for (int r = 0; r < 4; ++r)
              tT[(wn * 64 + j * 16 + lr) * 136 + wm * 64 + i * 16 + lq * 4 + r] =
                  f2bf(acc[i][j][r]);
        __syncthreads();
        int ct   = tid >> 1;
        int half = (tid & 1) * 64;
        u16* dst = (u16*)Cout + cb + (long)(n0 + ct) * ldc + m0 + half;
        const u16* srcl = &tT[ct * 136 + half];
#pragma unroll
        for (int q = 0; q < 8; ++q)
          *(u16v8*)(dst + q * 8) = *(const u16v8*)(srcl + q * 8);
      }
    }
  } else {
    // MODE 3: full-tile transposed bf16 store via LDS [128][136]
    u16* tT = (u16*)smem_c;
#pragma unroll
    for (int i = 0; i < 4; ++i)
#pragma unroll
      for (int j = 0; j < 4; ++j)
#pragma unroll
        for (int r = 0; r < 4; ++r)
          tT[(wn * 64 + j * 16 + lr) * 136 + wm * 64 + i * 16 + lq * 4 + r] =
              f2bf(acc[i][j][r]);
    __syncthreads();
    int ct   = tid >> 1;
    int half = (tid & 1) * 64;
    u16* dst = (u16*)Cout + cb + (long)(n0 + ct) * ldc + m0 + half;
    const u16* srcl = &tT[ct * 136 + half];
#pragma unroll
    for (int q = 0; q < 8; ++q)
      *(u16v8*)(dst + q * 8) = *(const u16v8*)(srcl + q * 8);
  }
}

// ------------- NT GEMM 64x128 (small GEMMs only) -------------
// MODE: 0=bf16 store. LDS 48KB. dbuf + counted vmcnt(6).
__global__ __launch_bounds__(256) void gemm64(
    const u16* __restrict__ A, const u16* __restrict__ B, u16* __restrict__ Cout,
    int K, int lda, int ldb, int ldc, long sA, long sB, long sC) {
  __shared__ __align__(16) char smem_c[49152];

  int gx = gridDim.x, gy = gridDim.y;
  int nwg = gx * gy * (int)gridDim.z;
  int flat = blockIdx.x + gx * (blockIdx.y + gy * blockIdx.z);
  if ((nwg & 7) == 0) { int q = nwg >> 3; flat = (flat & 7) * q + (flat >> 3); }
  int bx = flat % gx; int tmp = flat / gx; int by = tmp % gy; int b = tmp / gy;

  long n0 = (long)bx * 128;
  long m0 = (long)by * 64;
  const u16* Ag = A + (long)b * sA;
  const u16* Bg = B + (long)b * sB;

  int tid  = threadIdx.x;
  int lane = tid & 63;
  int wid  = tid >> 6;
  int wm = wid >> 1, wn = wid & 1;

  int srow = wid * 8 + (lane >> 3);
  int scol = (lane & 7) * 8;

  auto stageA = [&](u16* Asd, int k0) {
#pragma unroll
    for (int c = 0; c < 2; ++c) {
      int row = c * 32 + srow;
      __builtin_amdgcn_global_load_lds(
          (const __attribute__((address_space(1))) void*)(Ag + (m0 + row) * lda + k0 + scol),
          (__attribute__((address_space(3))) void*)(Asd + (c * 32 + wid * 8) * 64),
          16, 0, 0);
    }
  };
  auto stageB = [&](u16* Bsd, int k0) {
#pragma unroll
    for (int c = 0; c < 4; ++c) {
      int row = c * 32 + srow;
      __builtin_amdgcn_global_load_lds(
          (const __attribute__((address_space(1))) void*)(Bg + (n0 + row) * ldb + k0 + scol),
          (__attribute__((address_space(3))) void*)(Bsd + (c * 32 + wid * 8) * 64),
          16, 0, 0);
    }
  };

  f32x4 acc[2][4] = {};
  int nk = K >> 6;

  stageA((u16*)smem_c, 0);
  stageB((u16*)(smem_c + 16384), 0);

  for (int t = 0; t < nk; ++t) {
    u16* Asc = (u16*)(smem_c + (t & 1) * 8192);
    u16* Bsc = (u16*)(smem_c + 16384 + (t & 1) * 16384);
    u16* Asn = (u16*)(smem_c + ((t + 1) & 1) * 8192);
    u16* Bsn = (u16*)(smem_c + 16384 + ((t + 1) & 1) * 16384);
    bool more = (t + 1) < nk;
    if (more) {
      stageA(Asn, (t + 1) * 64);
      stageB(Bsn, (t + 1) * 64);
      asm volatile("s_waitcnt vmcnt(6)\n\ts_barrier" ::: "memory");
    } else {
      asm volatile("s_waitcnt vmcnt(0)\n\ts_barrier" ::: "memory");
    }
#pragma unroll
    for (int kk = 0; kk < 2; ++kk) {
      int kofs = kk * 32 + (lane >> 4) * 8;
      bf16x8 af[2], bfr[4];
#pragma unroll
      for (int i = 0; i < 2; ++i)
        af[i]  = *(const bf16x8*)&Asc[(wm * 32 + i * 16 + (lane & 15)) * 64 + kofs];
#pragma unroll
      for (int j = 0; j < 4; ++j)
        bfr[j] = *(const bf16x8*)&Bsc[(wn * 64 + j * 16 + (lane & 15)) * 64 + kofs];
#pragma unroll
      for (int i = 0; i < 2; ++i)
#pragma unroll
        for (int j = 0; j < 4; ++j)
          acc[i][j] = __builtin_amdgcn_mfma_f32_16x16x32_bf16(af[i], bfr[j], acc[i][j], 0, 0, 0);
    }
    asm volatile("s_barrier" ::: "memory");
  }

  int lq = lane >> 4;
  int lr = lane & 15;
  float* ep = (float*)(smem_c + wid * 4608);
  long cb  = (long)b * sC;
  int row0 = (int)m0 + wm * 32;
  int colb = (int)n0 + wn * 64;
#pragma unroll
  for (int i = 0; i < 2; ++i) {
#pragma unroll
    for (int j = 0; j < 4; ++j)
#pragma unroll
      for (int r = 0; r < 4; ++r)
        ep[(lq * 4 + r) * 72 + lr + j * 16] = acc[i][j][r];
#pragma unroll
    for (int p = 0; p < 4; ++p) {
      int rl = p * 4 + lq;
      f32x4 v = *(f32x4*)&ep[rl * 72 + lr * 4];
      long off = (long)(row0 + i * 16 + rl) * ldc + colb + lr * 4;
      u16v4 o;
#pragma unroll
      for (int t2 = 0; t2 < 4; ++t2) o[t2] = f2bf(v[t2]);
      *(u16v4*)(Cout + cb + off) = o;
    }
  }
}

// ------- logits GEMM with FUSED channel softmax, f32 A (reads h directly) -------
__global__ __launch_bounds__(256, 2) void gemm_sm(
    const float* __restrict__ A,  // [32768 x 512] f32 (h)
    const u16* __restrict__ Bw,   // [512 x 512] bf16 (w_attn)
    u16* __restrict__ C) {        // [32768 x 512] bf16 attn
  __shared__ __align__(16) char smem[73728];
  u16* As = (u16*)smem;                 // [64][64]
  u16* Bs = (u16*)(smem + 8192);        // [512][64]

  int nwg = gridDim.x;
  int flat = blockIdx.x;
  if ((nwg & 7) == 0) { int q = nwg >> 3; flat = (flat & 7) * q + (flat >> 3); }
  long m0 = (long)flat * 64;

  int tid = threadIdx.x;
  int lane = tid & 63;
  int wid = tid >> 6;

  int srow = wid * 8 + (lane >> 3);
  int scol = (lane & 7) * 8;
  int arow  = tid >> 2;          // 0..63
  int acolb = (tid & 3) * 16;    // f32 col base

  f32x4 acc[4][8] = {};

  for (int k0 = 0; k0 < 512; k0 += 64) {
    // A: reg-load f32, convert, ds_write
    const float* sp = A + (m0 + arow) * 512 + k0 + acolb;
    f32v4 x0 = *(const f32v4*)sp;
    f32v4 x1 = *(const f32v4*)(sp + 4);
    f32v4 x2 = *(const f32v4*)(sp + 8);
    f32v4 x3 = *(const f32v4*)(sp + 12);
#pragma unroll
    for (int c = 0; c < 16; ++c) {
      int row = c * 32 + srow;
      __builtin_amdgcn_global_load_lds(
          (const __attribute__((address_space(1))) void*)(Bw + (long)row * 512 + k0 + scol),
          (__attribute__((address_space(3))) void*)(Bs + (c * 32 + wid * 8) * 64),
          16, 0, 0);
    }
    u16v8 o0, o1;
    o0[0] = f2bf(x0[0]); o0[1] = f2bf(x0[1]); o0[2] = f2bf(x0[2]); o0[3] = f2bf(x0[3]);
    o0[4] = f2bf(x1[0]); o0[5] = f2bf(x1[1]); o0[6] = f2bf(x1[2]); o0[7] = f2bf(x1[3]);
    o1[0] = f2bf(x2[0]); o1[1] = f2bf(x2[1]); o1[2] = f2bf(x2[2]); o1[3] = f2bf(x2[3]);
    o1[4] = f2bf(x3[0]); o1[5] = f2bf(x3[1]); o1[6] = f2bf(x3[2]); o1[7] = f2bf(x3[3]);
    *(u16v8*)&As[arow * 64 + acolb] = o0;
    *(u16v8*)&As[arow * 64 + acolb + 8] = o1;
    __syncthreads();
#pragma unroll
    for (int kk = 0; kk < 2; ++kk) {
      int kofs = kk * 32 + (lane >> 4) * 8;
      bf16x8 af[4], bfr[8];
#pragma unroll
      for (int i = 0; i < 4; ++i)
        af[i] = *(const bf16x8*)&As[(i * 16 + (lane & 15)) * 64 + kofs];
#pragma unroll
      for (int j = 0; j < 8; ++j)
        bfr[j] = *(const bf16x8*)&Bs[(wid * 128 + j * 16 + (lane & 15)) * 64 + kofs];
#pragma unroll
      for (int i = 0; i < 4; ++i)
#pragma unroll
        for (int j = 0; j < 8; ++j)
          acc[i][j] = __builtin_amdgcn_mfma_f32_16x16x32_bf16(af[i], bfr[j], acc[i][j], 0, 0, 0);
    }
    __syncthreads();
  }

  int lq = lane >> 4, lr = lane & 15;
  float* sm = (float*)smem;            // [64][4]
  float* ss = (float*)(smem + 1024);   // [64][4]

#pragma unroll
  for (int i = 0; i < 4; ++i)
#pragma unroll
    for (int r = 0; r < 4; ++r) {
      float m = acc[i][0][r];
#pragma unroll
      for (int j = 1; j < 8; ++j) m = fmaxf(m, acc[i][j][r]);
#pragma unroll
      for (int o = 1; o < 16; o <<= 1) m = fmaxf(m, __shfl_xor(m, o, 16));
      if (lr == 0) sm[(i * 16 + lq * 4 + r) * 4 + wid] = m;
    }
  __syncthreads();
  float rinv[4][4];
#pragma unroll
  for (int i = 0; i < 4; ++i)
#pragma unroll
    for (int r = 0; r < 4; ++r) {
      f32v4 g4 = *(const f32v4*)&sm[(i * 16 + lq * 4 + r) * 4];
      float gm = fmaxf(fmaxf(g4[0], g4[1]), fmaxf(g4[2], g4[3]));
      float s = 0.f;
#pragma unroll
      for (int j = 0; j < 8; ++j) {
        float e = __expf(acc[i][j][r] - gm);
        acc[i][j][r] = e;
        s += e;
      }
#pragma unroll
      for (int o = 1; o < 16; o <<= 1) s += __shfl_xor(s, o, 16);
      if (lr == 0) ss[(i * 16 + lq * 4 + r) * 4 + wid] = s;
    }
  __syncthreads();
#pragma unroll
  for (int i = 0; i < 4; ++i)
#pragma unroll
    for (int r = 0; r < 4; ++r) {
      f32v4 g4 = *(const f32v4*)&ss[(i * 16 + lq * 4 + r) * 4];
      rinv[i][r] = 1.0f / (g4[0] + g4[1] + g4[2] + g4[3]);
    }
  __syncthreads();

  float* ep = (float*)(smem + wid * 4608);
#pragma unroll
  for (int i = 0; i < 4; ++i) {
#pragma unroll
    for (int jh = 0; jh < 2; ++jh) {
#pragma unroll
      for (int j = 0; j < 4; ++j)
#pragma unroll
        for (int r = 0; r < 4; ++r)
          ep[(lq * 4 + r) * 72 + lr + j * 16] = acc[i][jh * 4 + j][r] * rinv[i][r];
#pragma unroll
      for (int p = 0; p < 4; ++p) {
        int rl = p * 4 + lq;
        f32x4 v = *(f32x4*)&ep[rl * 72 + lr * 4];
        u16v4 o;
#pragma unroll
        for (int t = 0; t < 4; ++t) o[t] = f2bf(v[t]);
        *(u16v4*)&C[(m0 + i * 16 + rl) * 512 + wid * 128 + jh * 64 + lr * 4] = o;
      }
    }
  }
}

// ---------------- host ----------------
extern "C" void kernel_launch(void* const* d_in, const int* in_sizes, int n_in,
                              void* d_out, int out_size, void* d_ws, size_t ws_size,
                              hipStream_t stream) {
  (void)in_sizes; (void)n_in; (void)out_size; (void)ws_size;
  const float* h    = (const float*)d_in[0];
  const float* hret = (const float*)d_in[1];
  const float* Wc   = (const float*)d_in[2];
  const float* Wa   = (const float*)d_in[3];
  const float* Wk   = (const float*)d_in[4];
  const float* Wv   = (const float*)d_in[5];
  const float* Wo   = (const float*)d_in[6];
  float* out = (float*)d_out;
  char*  ws  = (char*)d_ws;

  constexpr long MB = 1024 * 1024;
  u16*   w_cond = (u16*)(ws + 0);
  u16*   w_attn = (u16*)(ws + 786432);
  u16*   w_k    = (u16*)(ws + 1310720);
  u16*   w_v    = (u16*)(ws + 1835008);
  u16*   w_out  = (u16*)(ws + 2359296);
  u16*   w_vT   = (u16*)(ws + 2883584);
  u16*   gparts = (u16*)(ws + 4 * MB);    // 32MB (live: Gram .. reduce8)
  u16*   attn   = (u16*)(ws + 36 * MB);
  u16*   g_bf   = (u16*)(ws + 68 * MB);
  u16*   u_mat  = (u16*)(ws + 72 * MB);
  u16*   v1     = (u16*)(ws + 73 * MB);
  u16*   f2t    = (u16*)(ws + 77 * MB);
  u16*   xt     = (u16*)(ws + 84 * MB);

  // 1) xt[:, 0:4096] = h^T (f32 read, bf16 transposed write)
  cvt_T<<<dim3(64, 8, 8), 256, 0, stream>>>(h, xt, 2097152L, 3145728L);
  // 2) all weights in one dispatch
  prep_weights<<<640, 256, 0, stream>>>(Wc, Wa, Wk, Wv, Wo,
      w_cond, w_attn, w_k, w_v, w_vT, w_out);

  // 3) hr = hret(f32) @ W_cond^T, 128^2 AF32, written TRANSPOSED into xt[:, 4096:6144]
  gemm_nt<3, true><<<dim3(16, 4, 8), 256, 0, stream>>>(hret, w_cond, xt + 4096, nullptr,
      768, 768, 768, 6144, 1572864L, 0, 3145728L, 0, 0, 1);

  // 4) attn = softmax(h @ W_attn^T) fused, reads h f32 directly (M=32768 flat)
  gemm_sm<<<512, 256, 0, stream>>>(h, w_attn, attn);

  // 5) Gram G = X^T X, TRIANGLE tiles only (10 pairs) + mirrored store, split-K=8
  gemm_nt<4, false><<<dim3(10, 1, 64), 256, 0, stream>>>(xt, xt, gparts, nullptr,
      768, 6144, 6144, 512, 3145728L, 3145728L, 2097152L, 262144L, 0, 8);
  reduce8_bf16<<<1024, 256, 0, stream>>>(gparts, g_bf);

  // 6) f2^T = W_out W_v G W_k^T (G symmetric):
  gemm64<<<dim3(4, 8, 1), 256, 0, stream>>>(w_out, w_vT, u_mat,
      512, 512, 512, 512, 0, 0, 0);
  gemm64<<<dim3(4, 8, 8), 256, 0, stream>>>(u_mat, g_bf, v1,
      512, 512, 512, 512, 0, 262144L, 262144L);
  gemm64<<<dim3(4, 8, 8), 256, 0, stream>>>(v1, w_k, f2t,
      512, 512, 512, 512, 262144L, 0, 262144L);

  // 7) out = h + attn @ f2  (128^2, fused residual, f32 out)
  gemm_nt<1, false><<<dim3(32, 4, 8), 256, 0, stream>>>(attn, f2t, out, h,
      512, 512, 512, 512, 2097152L, 262144L, 2097152L, 0, 2097152L, 1);
}

// Round 9
// 200.292 us; speedup vs baseline: 1.3655x; 1.0498x over previous
//
#include <hip/hip_runtime.h>
#include <hip/hip_bf16.h>

// Problem: B=8, N=4096, M=2048, IN=512, D=512, CTX=768
// out = h + attn @ f2,  attn = softmax(h W_a^T),  f2^T = W_out W_v G W_k^T,
// G = X^T X (symmetric), X = [h; h_retrieved W_c^T]  (all bf16 MFMA internally)

typedef unsigned short u16;
typedef __bf16 bf16x8 __attribute__((ext_vector_type(8)));
typedef float  f32x4  __attribute__((ext_vector_type(4)));
typedef float  f32v4  __attribute__((ext_vector_type(4)));
typedef u16    u16v4  __attribute__((ext_vector_type(4)));
typedef u16    u16v8  __attribute__((ext_vector_type(8)));

__device__ __forceinline__ u16 f2bf(float f) {
  unsigned u = __builtin_bit_cast(unsigned, f);
  u = u + 0x7FFFu + ((u >> 16) & 1u);   // RNE; inputs are finite
  return (u16)(u >> 16);
}
__device__ __forceinline__ float bf2f(u16 s) {
  return __builtin_bit_cast(float, (unsigned)s << 16);
}

// ------- f32 -> bf16 transpose only: xt[b][c][r] = bf16(h[b][r][c]) -------
__global__ __launch_bounds__(256) void cvt_T(const float* __restrict__ src,
                                             u16* __restrict__ dstT,
                                             long src_bs, long dstT_bs) {
  __shared__ u16 tile[64][72];
  long bz = blockIdx.z;
  const float* S = src + bz * src_bs;
  u16* DT = dstT + bz * dstT_bs;
  int r0 = blockIdx.x * 64;
  int c0 = blockIdx.y * 64;
  int t  = threadIdx.x;
  int tr = t >> 2;
  int tc = (t & 3) * 16;
  const float* sp = &S[(long)(r0 + tr) * 512 + c0 + tc];
#pragma unroll
  for (int q = 0; q < 2; ++q) {
    f32v4 a = *(const f32v4*)(sp + q * 8);
    f32v4 b = *(const f32v4*)(sp + q * 8 + 4);
    u16v8 o;
    o[0] = f2bf(a[0]); o[1] = f2bf(a[1]); o[2] = f2bf(a[2]); o[3] = f2bf(a[3]);
    o[4] = f2bf(b[0]); o[5] = f2bf(b[1]); o[6] = f2bf(b[2]); o[7] = f2bf(b[3]);
    *(u16v8*)&tile[tr][tc + q * 8] = o;
  }
  __syncthreads();
  int tr2 = t >> 3;
  int tc2 = (t & 7) * 8;
#pragma unroll
  for (int it = 0; it < 2; ++it) {
    int cr = it * 32 + tr2;
    u16v8 o;
#pragma unroll
    for (int j = 0; j < 8; ++j) o[j] = tile[tc2 + j][cr];
    *(u16v8*)&DT[(long)(c0 + cr) * 6144 + r0 + tc2] = o;
  }
}

// ------- all weight prep in ONE dispatch -------
__global__ __launch_bounds__(256) void prep_weights(
    const float* __restrict__ Wc, const float* __restrict__ Wa,
    const float* __restrict__ Wk, const float* __restrict__ Wv,
    const float* __restrict__ Wo,
    u16* __restrict__ wc, u16* __restrict__ wa, u16* __restrict__ wk,
    u16* __restrict__ wv, u16* __restrict__ wvT, u16* __restrict__ wo) {
  __shared__ u16 tile[64][72];
  int bx = blockIdx.x;
  int t = threadIdx.x;
  if (bx < 576) {
    const float* src; u16* dst; long base;
    if (bx < 192)      { src = Wc; dst = wc; base = (long)bx * 2048; }
    else if (bx < 320) { src = Wa; dst = wa; base = (long)(bx - 192) * 2048; }
    else if (bx < 448) { src = Wk; dst = wk; base = (long)(bx - 320) * 2048; }
    else               { src = Wo; dst = wo; base = (long)(bx - 448) * 2048; }
    long i = base + (long)t * 8;
    f32v4 a = *(const f32v4*)(src + i);
    f32v4 b = *(const f32v4*)(src + i + 4);
    u16v8 o;
    o[0] = f2bf(a[0]); o[1] = f2bf(a[1]); o[2] = f2bf(a[2]); o[3] = f2bf(a[3]);
    o[4] = f2bf(b[0]); o[5] = f2bf(b[1]); o[6] = f2bf(b[2]); o[7] = f2bf(b[3]);
    *(u16v8*)(dst + i) = o;
  } else {
    int b2 = bx - 576;
    int r0 = (b2 >> 3) * 64, c0 = (b2 & 7) * 64;
    int tr = t >> 2, tc = (t & 3) * 16;
    const float* sp = &Wv[(long)(r0 + tr) * 512 + c0 + tc];
#pragma unroll
    for (int q = 0; q < 2; ++q) {
      f32v4 a = *(const f32v4*)(sp + q * 8);
      f32v4 b = *(const f32v4*)(sp + q * 8 + 4);
      u16v8 o;
      o[0] = f2bf(a[0]); o[1] = f2bf(a[1]); o[2] = f2bf(a[2]); o[3] = f2bf(a[3]);
      o[4] = f2bf(b[0]); o[5] = f2bf(b[1]); o[6] = f2bf(b[2]); o[7] = f2bf(b[3]);
      *(u16v8*)&wv[(long)(r0 + tr) * 512 + c0 + tc + q * 8] = o;
      *(u16v8*)&tile[tr][tc + q * 8] = o;
    }
    __syncthreads();
    int tr2 = t >> 3, tc2 = (t & 7) * 8;
#pragma unroll
    for (int it = 0; it < 2; ++it) {
      int cr = it * 32 + tr2;
      u16v8 o;
#pragma unroll
      for (int j = 0; j < 8; ++j) o[j] = tile[tc2 + j][cr];
      *(u16v8*)&wvT[(long)(c0 + cr) * 512 + r0 + tc2] = o;
    }
  }
}

// -------- reduce 8 split-K bf16 slices -> bf16 (per batch 512x512) --------
__global__ __launch_bounds__(256) void reduce8_bf16(const u16* __restrict__ parts,
                                                    u16* __restrict__ out) {
  long i = (((long)blockIdx.x * 256) + threadIdx.x) * 8;
  long b = i >> 18;
  long r = i & 262143;
  const u16* p = parts + b * 2097152 + r;
  float acc[8] = {};
#pragma unroll
  for (int s = 0; s < 8; ++s) {
    u16v8 v = *(const u16v8*)(p + (long)s * 262144);
#pragma unroll
    for (int j = 0; j < 8; ++j) acc[j] += bf2f(v[j]);
  }
  u16v8 o;
#pragma unroll
  for (int j = 0; j < 8; ++j) o[j] = f2bf(acc[j]);
  *(u16v8*)(out + i) = o;
}

// ============ 256x256 multi-phase GEMM (m201-style, plain HIP) ============
// 512 threads = 8 waves (2M x 4N). BK=64. LDS 128KB: A[2buf][2half][128][64],
// B same at +32768 u16. T2 swizzle: chunk ^= row&7 on BOTH global-src and ds_read.
// Per K-tile: 4 phases {ds_read ; stage half-pair ; barrier ; MFMA16 ; barrier},
// vmcnt(0) only at tile top (stages issued >=2 phases earlier).
// MODE: 0 = bf16 store, 1 = f32 store + f32 residual.
template <int MODE>
__global__ __launch_bounds__(512, 2) void gemm256(
    const u16* __restrict__ A, const u16* __restrict__ B, void* __restrict__ Cout,
    const float* __restrict__ Res, int K, int lda, int ldb, int ldc,
    long sA, long sB, long sC, long sS, long sRes, int kslices) {
  __shared__ __align__(16) u16 lds[65536];   // 128 KB

  int gx = gridDim.x, gy = gridDim.y;
  int nwg = gx * gy * (int)gridDim.z;
  int flat = blockIdx.x + gx * (blockIdx.y + gy * blockIdx.z);
  if ((nwg & 7) == 0) { int q = nwg >> 3; flat = (flat & 7) * q + (flat >> 3); }
  int bx = flat % gx; int tmp = flat / gx; int by = tmp % gy; int z = tmp / gy;
  int b = z / kslices;
  int s = z - b * kslices;

  long m0 = (long)bx * 256;
  long n0 = (long)by * 256;
  const u16* Ag = A + (long)b * sA + (long)s * K;
  const u16* Bg = B + (long)b * sB + (long)s * K;

  int tid  = threadIdx.x;
  int lane = tid & 63;
  int wid  = tid >> 6;        // 0..7
  int wm = wid >> 2;          // 0..1  (M half)
  int wn = wid & 3;           // 0..3  (N quarter)
  int l15 = lane & 15, l16 = lane >> 4, l7 = lane & 7;

  // stage one 128x64 half-tile: linear LDS dest, swizzled global source
  auto stage_half = [&](bool isA, int buf, int h, int ktile) {
    const u16* G = isA ? Ag : Bg;
    long rb = (isA ? m0 : n0) + h * 128;
    int ldg = isA ? lda : ldb;
    u16* base = lds + (isA ? 0 : 32768) + buf * 16384 + h * 8192;
    int row_lo = wid * 8 + (lane >> 3);                  // 0..63
    int ce = ((lane & 7) ^ ((lane >> 3) & 7)) * 8;       // swizzled src col (elems)
#pragma unroll
    for (int q = 0; q < 2; ++q) {
      const u16* src = G + (rb + q * 64 + row_lo) * (long)ldg + ktile * 64 + ce;
      u16* dst = base + (q * 512 + wid * 64) * 8;        // wave-uniform; HW adds lane*16B
      __builtin_amdgcn_global_load_lds(
          (const __attribute__((address_space(1))) void*)src,
          (__attribute__((address_space(3))) void*)dst, 16, 0, 0);
    }
  };

  f32x4 acc[8][4] = {};
  int nk = K >> 6;

  // prologue: stage tile 0 into buf 0 (8 VMEM ops)
  stage_half(true,  0, 0, 0); stage_half(true,  0, 1, 0);
  stage_half(false, 0, 0, 0); stage_half(false, 0, 1, 0);

  for (int kt = 0; kt < nk; ++kt) {
    int cur = kt & 1, nxt = cur ^ 1;
    asm volatile("s_waitcnt vmcnt(0)\n\ts_barrier" ::: "memory");  // tile kt landed
    const u16* Ab = lds + cur * 16384 + wm * 8192;
    const u16* Bb = lds + 32768 + cur * 16384 + (wn >> 1) * 8192 + (wn & 1) * 4096;
    bool more = (kt + 1) < nk;
#pragma unroll
    for (int kk = 0; kk < 2; ++kk) {
      int csw = ((kk * 4 + l16) ^ l7) * 8;   // swizzled chunk (elems)
      bf16x8 bf[4];
#pragma unroll
      for (int j = 0; j < 4; ++j)
        bf[j] = *(const bf16x8*)&Bb[(j * 16 + l15) * 64 + csw];
#pragma unroll
      for (int frh = 0; frh < 2; ++frh) {
        bf16x8 af[4];
#pragma unroll
        for (int i = 0; i < 4; ++i)
          af[i] = *(const bf16x8*)&Ab[((frh * 4 + i) * 16 + l15) * 64 + csw];
        if (more) {
          if (kk == 0 && frh == 0) {
            stage_half(true, nxt, 0, kt + 1); stage_half(true, nxt, 1, kt + 1);
          } else if (kk == 0 && frh == 1) {
            stage_half(false, nxt, 0, kt + 1); stage_half(false, nxt, 1, kt + 1);
          }
        }
        asm volatile("s_barrier" ::: "memory");
        __builtin_amdgcn_s_setprio(1);
#pragma unroll
        for (int i = 0; i < 4; ++i)
#pragma unroll
          for (int j = 0; j < 4; ++j)
            acc[frh * 4 + i][j] = __builtin_amdgcn_mfma_f32_16x16x32_bf16(
                af[i], bf[j], acc[frh * 4 + i][j], 0, 0, 0);
        __builtin_amdgcn_s_setprio(0);
        asm volatile("s_barrier" ::: "memory");
      }
    }
  }

  // epilogue: LDS-staged coalesced stores (wave-private 16x72 f32 scratch)
  int lq = l16, lr = l15;
  float* ep = (float*)((char*)lds + wid * 4608);
  long cb  = (long)b * sC + (long)s * sS;
  int row0 = (int)m0 + wm * 128;
  int colb = (int)n0 + wn * 64;
#pragma unroll
  for (int fr = 0; fr < 8; ++fr) {
#pragma unroll
    for (int j = 0; j < 4; ++j)
#pragma unroll
      for (int r = 0; r < 4; ++r)
        ep[(lq * 4 + r) * 72 + lr + j * 16] = acc[fr][j][r];
#pragma unroll
    for (int p = 0; p < 4; ++p) {
      int rl = p * 4 + lq;
      f32x4 v = *(f32x4*)&ep[rl * 72 + lr * 4];
      long off = (long)(row0 + fr * 16 + rl) * ldc + colb + lr * 4;
      if (MODE == 0) {
        u16v4 o;
#pragma unroll
        for (int t2 = 0; t2 < 4; ++t2) o[t2] = f2bf(v[t2]);
        *(u16v4*)((u16*)Cout + cb + off) = o;
      } else {
        const float* R = Res + (long)b * sRes;
        f32v4 rv = *(const f32v4*)&R[off];
        f32v4 ov;
#pragma unroll
        for (int t2 = 0; t2 < 4; ++t2) ov[t2] = v[t2] + rv[t2];
        *(f32v4*)((float*)Cout + cb + off) = ov;
      }
    }
  }
}

// ------------- NT GEMM 128x128, dbuf + counted vmcnt (hr path only) -------------
// MODE 3 = bf16 TRANSPOSED store; AF32 = f32 A reg-staged with bf16 convert.
template <int MODE, bool AF32>
__global__ __launch_bounds__(256) void gemm_nt(
    const void* __restrict__ Ap, const u16* __restrict__ B, void* __restrict__ Cout,
    const float* __restrict__ Res, int K, int lda, int ldb, int ldc,
    long sA, long sB, long sC, long sS, long sRes, int kslices) {
  __shared__ __align__(16) char smem_c[65536];

  int gx = gridDim.x, gy = gridDim.y;
  int nwg = gx * gy * (int)gridDim.z;
  int flat = blockIdx.x + gx * (blockIdx.y + gy * blockIdx.z);
  if ((nwg & 7) == 0) { int q = nwg >> 3; flat = (flat & 7) * q + (flat >> 3); }
  int bx = flat % gx; int tmp = flat / gx; int by = tmp % gy; int z = tmp / gy;

  int b = z / kslices;
  int s = z - b * kslices;

  long m0 = (long)bx * 128;
  long n0 = (long)by * 128;

  const u16* Ag = (const u16*)Ap + (long)b * sA + (long)s * K;
  const float* Af = (const float*)Ap + (long)b * sA;
  const u16* Bg = B + (long)b * sB + (long)s * K;

  int tid  = threadIdx.x;
  int lane = tid & 63;
  int wid  = tid >> 6;
  int wm = wid >> 1, wn = wid & 1;

  int srow = wid * 8 + (lane >> 3);
  int scol = (lane & 7) * 8;
  int arow  = tid >> 1;
  int acolb = (tid & 1) * 32;

  auto stageA = [&](u16* Asd, int k0) {
#pragma unroll
    for (int c = 0; c < 4; ++c) {
      int row = c * 32 + srow;
      __builtin_amdgcn_global_load_lds(
          (const __attribute__((address_space(1))) void*)(Ag + (m0 + row) * lda + k0 + scol),
          (__attribute__((address_space(3))) void*)(Asd + (c * 32 + wid * 8) * 64),
          16, 0, 0);
    }
  };
  auto stageB = [&](u16* Bsd, int k0) {
#pragma unroll
    for (int c = 0; c < 4; ++c) {
      int row = c * 32 + srow;
      __builtin_amdgcn_global_load_lds(
          (const __attribute__((address_space(1))) void*)(Bg + (n0 + row) * ldb + k0 + scol),
          (__attribute__((address_space(3))) void*)(Bsd + (c * 32 + wid * 8) * 64),
          16, 0, 0);
    }
  };
  f32v4 xr[8];
  auto loadA = [&](int k0) {
    const float* sp = Af + (m0 + arow) * (long)lda + k0 + acolb;
#pragma unroll
    for (int q = 0; q < 8; ++q) xr[q] = *(const f32v4*)(sp + q * 4);
  };
  auto cvtA = [&](u16* Asd) {
#pragma unroll
    for (int q = 0; q < 4; ++q) {
      u16v8 o;
      o[0] = f2bf(xr[2*q][0]); o[1] = f2bf(xr[2*q][1]);
      o[2] = f2bf(xr[2*q][2]); o[3] = f2bf(xr[2*q][3]);
      o[4] = f2bf(xr[2*q+1][0]); o[5] = f2bf(xr[2*q+1][1]);
      o[6] = f2bf(xr[2*q+1][2]); o[7] = f2bf(xr[2*q+1][3]);
      *(u16v8*)&Asd[arow * 64 + acolb + q * 8] = o;
    }
  };

  f32x4 acc[4][4] = {};
  int nk = K >> 6;

  if constexpr (AF32) {
    loadA(0);
    cvtA((u16*)smem_c);
    asm volatile("s_waitcnt lgkmcnt(0)" ::: "memory");
  } else {
    stageA((u16*)smem_c, 0);
  }
  stageB((u16*)(smem_c + 32768), 0);

  for (int t = 0; t < nk; ++t) {
    u16* Asc = (u16*)(smem_c + (t & 1) * 16384);
    u16* Bsc = (u16*)(smem_c + 32768 + (t & 1) * 16384);
    u16* Asn = (u16*)(smem_c + ((t + 1) & 1) * 16384);
    u16* Bsn = (u16*)(smem_c + 32768 + ((t + 1) & 1) * 16384);
    bool more = (t + 1) < nk;
    if (more) {
      if constexpr (AF32) {
        loadA((t + 1) * 64);
        stageB(Bsn, (t + 1) * 64);
        asm volatile("s_waitcnt vmcnt(12)\n\ts_barrier" ::: "memory");
      } else {
        stageA(Asn, (t + 1) * 64);
        stageB(Bsn, (t + 1) * 64);
        asm volatile("s_waitcnt vmcnt(8)\n\ts_barrier" ::: "memory");
      }
    } else {
      asm volatile("s_waitcnt vmcnt(0)\n\ts_barrier" ::: "memory");
    }
#pragma unroll
    for (int kk = 0; kk < 2; ++kk) {
      int kofs = kk * 32 + (lane >> 4) * 8;
      bf16x8 af[4], bfr[4];
#pragma unroll
      for (int i = 0; i < 4; ++i) {
        af[i]  = *(const bf16x8*)&Asc[(wm * 64 + i * 16 + (lane & 15)) * 64 + kofs];
        bfr[i] = *(const bf16x8*)&Bsc[(wn * 64 + i * 16 + (lane & 15)) * 64 + kofs];
      }
#pragma unroll
      for (int i = 0; i < 4; ++i)
#pragma unroll
        for (int j = 0; j < 4; ++j)
          acc[i][j] = __builtin_amdgcn_mfma_f32_16x16x32_bf16(af[i], bfr[j], acc[i][j], 0, 0, 0);
    }
    if constexpr (AF32) {
      if (more) cvtA(Asn);
      asm volatile("s_waitcnt lgkmcnt(0)\n\ts_barrier" ::: "memory");
    } else {
      asm volatile("s_barrier" ::: "memory");
    }
  }

  long cb = (long)b * sC + (long)s * sS;
  int lq = lane >> 4;
  int lr = lane & 15;

  if constexpr (MODE == 3) {
    // transposed bf16 store via LDS [128][136]
    u16* tT = (u16*)smem_c;
#pragma unroll
    for (int i = 0; i < 4; ++i)
#pragma unroll
      for (int j = 0; j < 4; ++j)
#pragma unroll
        for (int r = 0; r < 4; ++r)
          tT[(wn * 64 + j * 16 + lr) * 136 + wm * 64 + i * 16 + lq * 4 + r] =
              f2bf(acc[i][j][r]);
    __syncthreads();
    int ct   = tid >> 1;
    int half = (tid & 1) * 64;
    u16* dst = (u16*)Cout + cb + (long)(n0 + ct) * ldc + m0 + half;
    const u16* srcl = &tT[ct * 136 + half];
#pragma unroll
    for (int q = 0; q < 8; ++q)
      *(u16v8*)(dst + q * 8) = *(const u16v8*)(srcl + q * 8);
  } else {
    float* ep = (float*)(smem_c + wid * 4608);
    int row0 = (int)m0 + wm * 64;
    int colb = (int)n0 + wn * 64;
#pragma unroll
    for (int i = 0; i < 4; ++i) {
#pragma unroll
      for (int j = 0; j < 4; ++j)
#pragma unroll
        for (int r = 0; r < 4; ++r)
          ep[(lq * 4 + r) * 72 + lr + j * 16] = acc[i][j][r];
#pragma unroll
      for (int p = 0; p < 4; ++p) {
        int rl = p * 4 + lq;
        f32x4 v = *(f32x4*)&ep[rl * 72 + lr * 4];
        long off = (long)(row0 + i * 16 + rl) * ldc + colb + lr * 4;
        u16v4 o;
#pragma unroll
        for (int t2 = 0; t2 < 4; ++t2) o[t2] = f2bf(v[t2]);
        *(u16v4*)((u16*)Cout + cb + off) = o;
      }
    }
  }
}

// ------------- NT GEMM 64x128 (small GEMMs only) -------------
__global__ __launch_bounds__(256) void gemm64(
    const u16* __restrict__ A, const u16* __restrict__ B, u16* __restrict__ Cout,
    int K, int lda, int ldb, int ldc, long sA, long sB, long sC) {
  __shared__ __align__(16) char smem_c[49152];

  int gx = gridDim.x, gy = gridDim.y;
  int nwg = gx * gy * (int)gridDim.z;
  int flat = blockIdx.x + gx * (blockIdx.y + gy * blockIdx.z);
  if ((nwg & 7) == 0) { int q = nwg >> 3; flat = (flat & 7) * q + (flat >> 3); }
  int bx = flat % gx; int tmp = flat / gx; int by = tmp % gy; int b = tmp / gy;

  long n0 = (long)bx * 128;
  long m0 = (long)by * 64;
  const u16* Ag = A + (long)b * sA;
  const u16* Bg = B + (long)b * sB;

  int tid  = threadIdx.x;
  int lane = tid & 63;
  int wid  = tid >> 6;
  int wm = wid >> 1, wn = wid & 1;

  int srow = wid * 8 + (lane >> 3);
  int scol = (lane & 7) * 8;

  auto stageA = [&](u16* Asd, int k0) {
#pragma unroll
    for (int c = 0; c < 2; ++c) {
      int row = c * 32 + srow;
      __builtin_amdgcn_global_load_lds(
          (const __attribute__((address_space(1))) void*)(Ag + (m0 + row) * lda + k0 + scol),
          (__attribute__((address_space(3))) void*)(Asd + (c * 32 + wid * 8) * 64),
          16, 0, 0);
    }
  };
  auto stageB = [&](u16* Bsd, int k0) {
#pragma unroll
    for (int c = 0; c < 4; ++c) {
      int row = c * 32 + srow;
      __builtin_amdgcn_global_load_lds(
          (const __attribute__((address_space(1))) void*)(Bg + (n0 + row) * ldb + k0 + scol),
          (__attribute__((address_space(3))) void*)(Bsd + (c * 32 + wid * 8) * 64),
          16, 0, 0);
    }
  };

  f32x4 acc[2][4] = {};
  int nk = K >> 6;

  stageA((u16*)smem_c, 0);
  stageB((u16*)(smem_c + 16384), 0);

  for (int t = 0; t < nk; ++t) {
    u16* Asc = (u16*)(smem_c + (t & 1) * 8192);
    u16* Bsc = (u16*)(smem_c + 16384 + (t & 1) * 16384);
    u16* Asn = (u16*)(smem_c + ((t + 1) & 1) * 8192);
    u16* Bsn = (u16*)(smem_c + 16384 + ((t + 1) & 1) * 16384);
    bool more = (t + 1) < nk;
    if (more) {
      stageA(Asn, (t + 1) * 64);
      stageB(Bsn, (t + 1) * 64);
      asm volatile("s_waitcnt vmcnt(6)\n\ts_barrier" ::: "memory");
    } else {
      asm volatile("s_waitcnt vmcnt(0)\n\ts_barrier" ::: "memory");
    }
#pragma unroll
    for (int kk = 0; kk < 2; ++kk) {
      int kofs = kk * 32 + (lane >> 4) * 8;
      bf16x8 af[2], bfr[4];
#pragma unroll
      for (int i = 0; i < 2; ++i)
        af[i]  = *(const bf16x8*)&Asc[(wm * 32 + i * 16 + (lane & 15)) * 64 + kofs];
#pragma unroll
      for (int j = 0; j < 4; ++j)
        bfr[j] = *(const bf16x8*)&Bsc[(wn * 64 + j * 16 + (lane & 15)) * 64 + kofs];
#pragma unroll
      for (int i = 0; i < 2; ++i)
#pragma unroll
        for (int j = 0; j < 4; ++j)
          acc[i][j] = __builtin_amdgcn_mfma_f32_16x16x32_bf16(af[i], bfr[j], acc[i][j], 0, 0, 0);
    }
    asm volatile("s_barrier" ::: "memory");
  }

  int lq = lane >> 4;
  int lr = lane & 15;
  float* ep = (float*)(smem_c + wid * 4608);
  long cb  = (long)b * sC;
  int row0 = (int)m0 + wm * 32;
  int colb = (int)n0 + wn * 64;
#pragma unroll
  for (int i = 0; i < 2; ++i) {
#pragma unroll
    for (int j = 0; j < 4; ++j)
#pragma unroll
      for (int r = 0; r < 4; ++r)
        ep[(lq * 4 + r) * 72 + lr + j * 16] = acc[i][j][r];
#pragma unroll
    for (int p = 0; p < 4; ++p) {
      int rl = p * 4 + lq;
      f32x4 v = *(f32x4*)&ep[rl * 72 + lr * 4];
      long off = (long)(row0 + i * 16 + rl) * ldc + colb + lr * 4;
      u16v4 o;
#pragma unroll
      for (int t2 = 0; t2 < 4; ++t2) o[t2] = f2bf(v[t2]);
      *(u16v4*)(Cout + cb + off) = o;
    }
  }
}

// ------- logits GEMM with FUSED channel softmax, f32 A (reads h directly) -------
__global__ __launch_bounds__(256, 2) void gemm_sm(
    const float* __restrict__ A,  // [32768 x 512] f32 (h)
    const u16* __restrict__ Bw,   // [512 x 512] bf16 (w_attn)
    u16* __restrict__ C) {        // [32768 x 512] bf16 attn
  __shared__ __align__(16) char smem[73728];
  u16* As = (u16*)smem;                 // [64][64]
  u16* Bs = (u16*)(smem + 8192);        // [512][64]

  int nwg = gridDim.x;
  int flat = blockIdx.x;
  if ((nwg & 7) == 0) { int q = nwg >> 3; flat = (flat & 7) * q + (flat >> 3); }
  long m0 = (long)flat * 64;

  int tid = threadIdx.x;
  int lane = tid & 63;
  int wid = tid >> 6;

  int srow = wid * 8 + (lane >> 3);
  int scol = (lane & 7) * 8;
  int arow  = tid >> 2;
  int acolb = (tid & 3) * 16;

  f32x4 acc[4][8] = {};

  for (int k0 = 0; k0 < 512; k0 += 64) {
    const float* sp = A + (m0 + arow) * 512 + k0 + acolb;
    f32v4 x0 = *(const f32v4*)sp;
    f32v4 x1 = *(const f32v4*)(sp + 4);
    f32v4 x2 = *(const f32v4*)(sp + 8);
    f32v4 x3 = *(const f32v4*)(sp + 12);
#pragma unroll
    for (int c = 0; c < 16; ++c) {
      int row = c * 32 + srow;
      __builtin_amdgcn_global_load_lds(
          (const __attribute__((address_space(1))) void*)(Bw + (long)row * 512 + k0 + scol),
          (__attribute__((address_space(3))) void*)(Bs + (c * 32 + wid * 8) * 64),
          16, 0, 0);
    }
    u16v8 o0, o1;
    o0[0] = f2bf(x0[0]); o0[1] = f2bf(x0[1]); o0[2] = f2bf(x0[2]); o0[3] = f2bf(x0[3]);
    o0[4] = f2bf(x1[0]); o0[5] = f2bf(x1[1]); o0[6] = f2bf(x1[2]); o0[7] = f2bf(x1[3]);
    o1[0] = f2bf(x2[0]); o1[1] = f2bf(x2[1]); o1[2] = f2bf(x2[2]); o1[3] = f2bf(x2[3]);
    o1[4] = f2bf(x3[0]); o1[5] = f2bf(x3[1]); o1[6] = f2bf(x3[2]); o1[7] = f2bf(x3[3]);
    *(u16v8*)&As[arow * 64 + acolb] = o0;
    *(u16v8*)&As[arow * 64 + acolb + 8] = o1;
    __syncthreads();
#pragma unroll
    for (int kk = 0; kk < 2; ++kk) {
      int kofs = kk * 32 + (lane >> 4) * 8;
      bf16x8 af[4], bfr[8];
#pragma unroll
      for (int i = 0; i < 4; ++i)
        af[i] = *(const bf16x8*)&As[(i * 16 + (lane & 15)) * 64 + kofs];
#pragma unroll
      for (int j = 0; j < 8; ++j)
        bfr[j] = *(const bf16x8*)&Bs[(wid * 128 + j * 16 + (lane & 15)) * 64 + kofs];
#pragma unroll
      for (int i = 0; i < 4; ++i)
#pragma unroll
        for (int j = 0; j < 8; ++j)
          acc[i][j] = __builtin_amdgcn_mfma_f32_16x16x32_bf16(af[i], bfr[j], acc[i][j], 0, 0, 0);
    }
    __syncthreads();
  }

  int lq = lane >> 4, lr = lane & 15;
  float* sm = (float*)smem;            // [64][4]
  float* ss = (float*)(smem + 1024);   // [64][4]

#pragma unroll
  for (int i = 0; i < 4; ++i)
#pragma unroll
    for (int r = 0; r < 4; ++r) {
      float m = acc[i][0][r];
#pragma unroll
      for (int j = 1; j < 8; ++j) m = fmaxf(m, acc[i][j][r]);
#pragma unroll
      for (int o = 1; o < 16; o <<= 1) m = fmaxf(m, __shfl_xor(m, o, 16));
      if (lr == 0) sm[(i * 16 + lq * 4 + r) * 4 + wid] = m;
    }
  __syncthreads();
  float rinv[4][4];
#pragma unroll
  for (int i = 0; i < 4; ++i)
#pragma unroll
    for (int r = 0; r < 4; ++r) {
      f32v4 g4 = *(const f32v4*)&sm[(i * 16 + lq * 4 + r) * 4];
      float gm = fmaxf(fmaxf(g4[0], g4[1]), fmaxf(g4[2], g4[3]));
      float s = 0.f;
#pragma unroll
      for (int j = 0; j < 8; ++j) {
        float e = __expf(acc[i][j][r] - gm);
        acc[i][j][r] = e;
        s += e;
      }
#pragma unroll
      for (int o = 1; o < 16; o <<= 1) s += __shfl_xor(s, o, 16);
      if (lr == 0) ss[(i * 16 + lq * 4 + r) * 4 + wid] = s;
    }
  __syncthreads();
#pragma unroll
  for (int i = 0; i < 4; ++i)
#pragma unroll
    for (int r = 0; r < 4; ++r) {
      f32v4 g4 = *(const f32v4*)&ss[(i * 16 + lq * 4 + r) * 4];
      rinv[i][r] = 1.0f / (g4[0] + g4[1] + g4[2] + g4[3]);
    }
  __syncthreads();

  float* ep = (float*)(smem + wid * 4608);
#pragma unroll
  for (int i = 0; i < 4; ++i) {
#pragma unroll
    for (int jh = 0; jh < 2; ++jh) {
#pragma unroll
      for (int j = 0; j < 4; ++j)
#pragma unroll
        for (int r = 0; r < 4; ++r)
          ep[(lq * 4 + r) * 72 + lr + j * 16] = acc[i][jh * 4 + j][r] * rinv[i][r];
#pragma unroll
      for (int p = 0; p < 4; ++p) {
        int rl = p * 4 + lq;
        f32x4 v = *(f32x4*)&ep[rl * 72 + lr * 4];
        u16v4 o;
#pragma unroll
        for (int t = 0; t < 4; ++t) o[t] = f2bf(v[t]);
        *(u16v4*)&C[(m0 + i * 16 + rl) * 512 + wid * 128 + jh * 64 + lr * 4] = o;
      }
    }
  }
}

// ---------------- host ----------------
extern "C" void kernel_launch(void* const* d_in, const int* in_sizes, int n_in,
                              void* d_out, int out_size, void* d_ws, size_t ws_size,
                              hipStream_t stream) {
  (void)in_sizes; (void)n_in; (void)out_size; (void)ws_size;
  const float* h    = (const float*)d_in[0];
  const float* hret = (const float*)d_in[1];
  const float* Wc   = (const float*)d_in[2];
  const float* Wa   = (const float*)d_in[3];
  const float* Wk   = (const float*)d_in[4];
  const float* Wv   = (const float*)d_in[5];
  const float* Wo   = (const float*)d_in[6];
  float* out = (float*)d_out;
  char*  ws  = (char*)d_ws;

  constexpr long MB = 1024 * 1024;
  u16*   w_cond = (u16*)(ws + 0);
  u16*   w_attn = (u16*)(ws + 786432);
  u16*   w_k    = (u16*)(ws + 1310720);
  u16*   w_v    = (u16*)(ws + 1835008);
  u16*   w_out  = (u16*)(ws + 2359296);
  u16*   w_vT   = (u16*)(ws + 2883584);
  u16*   gparts = (u16*)(ws + 4 * MB);    // 32MB (live: Gram .. reduce8)
  u16*   attn   = (u16*)(ws + 36 * MB);
  u16*   g_bf   = (u16*)(ws + 68 * MB);
  u16*   u_mat  = (u16*)(ws + 72 * MB);
  u16*   v1     = (u16*)(ws + 73 * MB);
  u16*   f2t    = (u16*)(ws + 77 * MB);
  u16*   xt     = (u16*)(ws + 84 * MB);

  // 1) xt[:, 0:4096] = h^T (f32 read, bf16 transposed write)
  cvt_T<<<dim3(64, 8, 8), 256, 0, stream>>>(h, xt, 2097152L, 3145728L);
  // 2) all weights in one dispatch
  prep_weights<<<640, 256, 0, stream>>>(Wc, Wa, Wk, Wv, Wo,
      w_cond, w_attn, w_k, w_v, w_vT, w_out);

  // 3) hr = hret(f32) @ W_cond^T, 128^2 AF32, written TRANSPOSED into xt[:, 4096:6144]
  gemm_nt<3, true><<<dim3(16, 4, 8), 256, 0, stream>>>(hret, w_cond, xt + 4096, nullptr,
      768, 768, 768, 6144, 1572864L, 0, 3145728L, 0, 0, 1);

  // 4) attn = softmax(h @ W_attn^T) fused, reads h f32 directly (M=32768 flat)
  gemm_sm<<<512, 256, 0, stream>>>(h, w_attn, attn);

  // 5) Gram G = X^T X via 256^2 multi-phase kernel, split-K=8, grid 256 = 1/CU
  gemm256<0><<<dim3(2, 2, 64), 512, 0, stream>>>(xt, xt, gparts, nullptr,
      768, 6144, 6144, 512, 3145728L, 3145728L, 2097152L, 262144L, 0, 8);
  reduce8_bf16<<<1024, 256, 0, stream>>>(gparts, g_bf);

  // 6) f2^T = W_out W_v G W_k^T (G symmetric):
  gemm64<<<dim3(4, 8, 1), 256, 0, stream>>>(w_out, w_vT, u_mat,
      512, 512, 512, 512, 0, 0, 0);
  gemm64<<<dim3(4, 8, 8), 256, 0, stream>>>(u_mat, g_bf, v1,
      512, 512, 512, 512, 0, 262144L, 262144L);
  gemm64<<<dim3(4, 8, 8), 256, 0, stream>>>(v1, w_k, f2t,
      512, 512, 512, 512, 262144L, 0, 262144L);

  // 7) out = h + attn @ f2  (256^2 multi-phase, fused residual, grid 256 = 1/CU)
  gemm256<1><<<dim3(16, 2, 8), 512, 0, stream>>>(attn, f2t, out, h,
      512, 512, 512, 512, 2097152L, 262144L, 2097152L, 0, 2097152L, 1);
}